// Round 1
// baseline (2138.271 us; speedup 1.0000x reference)
//
#include <hip/hip_runtime.h>
#include <hip/hip_bf16.h>

// Problem constants
#define B 2
#define C 512
#define H 8
#define D 64
#define S 4096           // 64*64 tokens
#define O3 1536          // 3*C
#define SCALE 0.125f     // D^-0.5 = 1/8

// Workspace layout (floats):
//   q  : [B][H][S][D]  @ 0
//   k  : [B][H][S][D]  @ QSZ
//   v  : [B][H][S][D]  @ 2*QSZ
//   ao : [B][H][S][D]  @ 3*QSZ   (attention output, head-major)
#define QSZ (B * H * S * D)   // 4,194,304 floats (16 MB); total 64 MB

// ---------------------------------------------------------------------------
// Kernel 1: QKV projection.
// qkv[b][m][o] = sum_k x[b][k][m] * w_qkv[o][k],  o in [0,1536)
// x is [b][c][s] so A^T is contiguous in m (coalesced loads).
// Output written directly into head-major q/k/v workspace.
// Tile: 64 (m) x 64 (o), K-tile 32. 256 threads, 4x4 micro-tile each.
// ---------------------------------------------------------------------------
__global__ __launch_bounds__(256) void qkv_kernel(const float* __restrict__ x,
                                                  const float* __restrict__ w,
                                                  float* __restrict__ ws) {
    const int m0 = blockIdx.x * 64;
    const int o0 = blockIdx.y * 64;
    const int b  = blockIdx.z;
    const int tid = threadIdx.x;
    const int tx = tid & 15, ty = tid >> 4;

    __shared__ float As[32][64];   // [kk][mm]  (k-major, natural from x)
    __shared__ float Bs[64][36];   // [oo][kk]  (+pad: 36 mod 32 = 4 -> 2-way max)

    float acc[4][4] = {};          // [i: m][j: o]
    const float* xb = x + (size_t)b * C * S;

    for (int k0 = 0; k0 < C; k0 += 32) {
        #pragma unroll
        for (int i = 0; i < 2; ++i) {
            int f = tid + i * 256;               // 512 float4s for As
            int kk = f >> 4, mv = f & 15;
            *(float4*)&As[kk][mv * 4] =
                *(const float4*)&xb[(size_t)(k0 + kk) * S + m0 + mv * 4];
        }
        #pragma unroll
        for (int i = 0; i < 2; ++i) {
            int f = tid + i * 256;               // 512 float4s for Bs
            int oo = f >> 3, kv = f & 7;
            *(float4*)&Bs[oo][kv * 4] =
                *(const float4*)&w[(size_t)(o0 + oo) * C + k0 + kv * 4];
        }
        __syncthreads();
        #pragma unroll
        for (int kk4 = 0; kk4 < 8; ++kk4) {
            float4 b4[4];
            #pragma unroll
            for (int j = 0; j < 4; ++j) b4[j] = *(float4*)&Bs[tx * 4 + j][kk4 * 4];
            #pragma unroll
            for (int kkk = 0; kkk < 4; ++kkk) {
                float4 a4 = *(float4*)&As[kk4 * 4 + kkk][ty * 4];
                float av[4] = {a4.x, a4.y, a4.z, a4.w};
                #pragma unroll
                for (int i = 0; i < 4; ++i) {
                    #pragma unroll
                    for (int j = 0; j < 4; ++j)
                        acc[i][j] += av[i] * ((const float*)&b4[j])[kkk];
                }
            }
        }
        __syncthreads();
    }

    // o-tile (64 wide, 64-aligned) lies entirely inside one of q/k/v and one head
    const int t = o0 >> 9;          // 0=q, 1=k, 2=v
    const int h = (o0 & 511) >> 6;  // head index; dd base is 0
    float* dst = ws + (size_t)t * QSZ + (size_t)(b * H + h) * S * D;
    #pragma unroll
    for (int i = 0; i < 4; ++i) {
        int m = m0 + ty * 4 + i;
        float4 val = {acc[i][0], acc[i][1], acc[i][2], acc[i][3]};
        *(float4*)&dst[(size_t)m * D + tx * 4] = val;   // coalesced over tx
    }
}

// ---------------------------------------------------------------------------
// Kernel 2: flash attention, fp32.
// One block per (q-tile of 64 rows, head, batch). Online softmax over 64
// K/V tiles of 64 rows. 256 threads; thread (ty,tx) owns 4 q-rows x 4 cols.
// ---------------------------------------------------------------------------
__global__ __launch_bounds__(256) void attn_kernel(float* __restrict__ ws) {
    const int q0 = blockIdx.x * 64;
    const int h  = blockIdx.y;
    const int b  = blockIdx.z;
    const int tid = threadIdx.x;
    const int tx = tid & 15, ty = tid >> 4;
    const size_t bh = (size_t)(b * H + h) * S * D;

    const float* qg = ws + bh;
    const float* kg = ws + (size_t)QSZ + bh;
    const float* vg = ws + 2 * (size_t)QSZ + bh;
    float*       og = ws + 3 * (size_t)QSZ + bh;

    __shared__ float Qs[64][68];   // [r][d]   pad 68: 2-way max on b128 reads
    __shared__ float Ks[64][68];   // [c][d]
    __shared__ float Vs[64][68];   // [kk][d]
    __shared__ float Ps[64][68];   // [r][kk]

    #pragma unroll
    for (int i = 0; i < 4; ++i) {
        int f = tid + i * 256;
        int r = f >> 4, kv = f & 15;
        *(float4*)&Qs[r][kv * 4] =
            *(const float4*)&qg[(size_t)(q0 + r) * D + kv * 4];
    }

    float m_run[4], l_run[4], O[4][4];
    #pragma unroll
    for (int i = 0; i < 4; ++i) {
        m_run[i] = -1e30f; l_run[i] = 0.f;
        #pragma unroll
        for (int j = 0; j < 4; ++j) O[i][j] = 0.f;
    }

    for (int kt = 0; kt < S / 64; ++kt) {
        #pragma unroll
        for (int i = 0; i < 4; ++i) {
            int f = tid + i * 256;
            int r = f >> 4, kv = f & 15;
            *(float4*)&Ks[r][kv * 4] =
                *(const float4*)&kg[(size_t)(kt * 64 + r) * D + kv * 4];
            *(float4*)&Vs[r][kv * 4] =
                *(const float4*)&vg[(size_t)(kt * 64 + r) * D + kv * 4];
        }
        __syncthreads();

        // S = (Q K^T) — 4x4 per thread over d=64
        float s[4][4] = {};
        #pragma unroll
        for (int kk4 = 0; kk4 < 16; ++kk4) {
            float4 a4[4], b4[4];
            #pragma unroll
            for (int i = 0; i < 4; ++i) a4[i] = *(float4*)&Qs[ty * 4 + i][kk4 * 4];
            #pragma unroll
            for (int j = 0; j < 4; ++j) b4[j] = *(float4*)&Ks[tx * 4 + j][kk4 * 4];
            #pragma unroll
            for (int i = 0; i < 4; ++i) {
                #pragma unroll
                for (int j = 0; j < 4; ++j) {
                    s[i][j] += a4[i].x * b4[j].x + a4[i].y * b4[j].y +
                               a4[i].z * b4[j].z + a4[i].w * b4[j].w;
                }
            }
        }

        // online softmax update (row stats across the 16 tx lanes)
        #pragma unroll
        for (int i = 0; i < 4; ++i) {
            #pragma unroll
            for (int j = 0; j < 4; ++j) s[i][j] *= SCALE;
            float mt = fmaxf(fmaxf(s[i][0], s[i][1]), fmaxf(s[i][2], s[i][3]));
            #pragma unroll
            for (int off = 1; off < 16; off <<= 1)
                mt = fmaxf(mt, __shfl_xor(mt, off, 64));
            float mn = fmaxf(m_run[i], mt);
            float alpha = __expf(m_run[i] - mn);
            float lt = 0.f;
            #pragma unroll
            for (int j = 0; j < 4; ++j) { s[i][j] = __expf(s[i][j] - mn); lt += s[i][j]; }
            #pragma unroll
            for (int off = 1; off < 16; off <<= 1)
                lt += __shfl_xor(lt, off, 64);
            l_run[i] = l_run[i] * alpha + lt;
            m_run[i] = mn;
            #pragma unroll
            for (int j = 0; j < 4; ++j) O[i][j] *= alpha;
            #pragma unroll
            for (int j = 0; j < 4; ++j) Ps[ty * 4 + i][tx * 4 + j] = s[i][j];
        }
        __syncthreads();

        // O += P @ V  (P rows full-64 via LDS; V[kk][d] float4 over d)
        #pragma unroll
        for (int kk4 = 0; kk4 < 16; ++kk4) {
            float4 pa[4];
            #pragma unroll
            for (int i = 0; i < 4; ++i) pa[i] = *(float4*)&Ps[ty * 4 + i][kk4 * 4];
            #pragma unroll
            for (int kkk = 0; kkk < 4; ++kkk) {
                float4 v4 = *(float4*)&Vs[kk4 * 4 + kkk][tx * 4];
                #pragma unroll
                for (int i = 0; i < 4; ++i) {
                    float p = ((const float*)&pa[i])[kkk];
                    O[i][0] += p * v4.x; O[i][1] += p * v4.y;
                    O[i][2] += p * v4.z; O[i][3] += p * v4.w;
                }
            }
        }
        __syncthreads();
    }

    #pragma unroll
    for (int i = 0; i < 4; ++i) {
        float inv = 1.0f / l_run[i];
        float4 val = {O[i][0] * inv, O[i][1] * inv, O[i][2] * inv, O[i][3] * inv};
        *(float4*)&og[(size_t)(q0 + ty * 4 + i) * D + tx * 4] = val;
    }
}

// ---------------------------------------------------------------------------
// Kernel 3: output projection + bias, writes transposed to [b][c][s].
// out[b][cc][m] = sum_k ao[b][m][k] * w_out[cc][k] + b_out[cc]
// where ao "k" index maps to head-major workspace: k = h*64+dd.
// Tile 64 (m) x 64 (cc), K-tile 32. Thread maps: ty->cc, tx->m (coalesced
// float4 stores along m).
// ---------------------------------------------------------------------------
__global__ __launch_bounds__(256) void oproj_kernel(const float* __restrict__ ws,
                                                    const float* __restrict__ w_out,
                                                    const float* __restrict__ b_out,
                                                    float* __restrict__ out) {
    const int m0 = blockIdx.x * 64;
    const int c0 = blockIdx.y * 64;
    const int b  = blockIdx.z;
    const int tid = threadIdx.x;
    const int tx = tid & 15, ty = tid >> 4;
    const float* ao = ws + 3 * (size_t)QSZ + (size_t)b * H * S * D;

    __shared__ float As[64][36];   // [mm][kk]
    __shared__ float Bs[64][36];   // [cc][kk]

    float acc[4][4] = {};          // [i: cc][j: m]

    for (int k0 = 0; k0 < C; k0 += 32) {
        const int hh = k0 >> 6, dd0 = k0 & 63;     // K-tile sits inside one head
        const float* ab = ao + (size_t)hh * S * D + dd0;
        #pragma unroll
        for (int i = 0; i < 2; ++i) {
            int f = tid + i * 256;
            int mm = f >> 3, kv = f & 7;
            *(float4*)&As[mm][kv * 4] =
                *(const float4*)&ab[(size_t)(m0 + mm) * D + kv * 4];
            *(float4*)&Bs[mm][kv * 4] =
                *(const float4*)&w_out[(size_t)(c0 + mm) * C + k0 + kv * 4];
        }
        __syncthreads();
        #pragma unroll
        for (int kk4 = 0; kk4 < 8; ++kk4) {
            float4 a4[4], b4[4];
            #pragma unroll
            for (int j = 0; j < 4; ++j) a4[j] = *(float4*)&As[tx * 4 + j][kk4 * 4];
            #pragma unroll
            for (int i = 0; i < 4; ++i) b4[i] = *(float4*)&Bs[ty * 4 + i][kk4 * 4];
            #pragma unroll
            for (int i = 0; i < 4; ++i) {
                #pragma unroll
                for (int j = 0; j < 4; ++j) {
                    acc[i][j] += a4[j].x * b4[i].x + a4[j].y * b4[i].y +
                                 a4[j].z * b4[i].z + a4[j].w * b4[i].w;
                }
            }
        }
        __syncthreads();
    }

    #pragma unroll
    for (int i = 0; i < 4; ++i) {
        int cc = c0 + ty * 4 + i;
        float bias = b_out[cc];
        float4 val = {acc[i][0] + bias, acc[i][1] + bias,
                      acc[i][2] + bias, acc[i][3] + bias};
        *(float4*)&out[(size_t)b * C * S + (size_t)cc * S + m0 + tx * 4] = val;
    }
}

// ---------------------------------------------------------------------------
extern "C" void kernel_launch(void* const* d_in, const int* in_sizes, int n_in,
                              void* d_out, int out_size, void* d_ws, size_t ws_size,
                              hipStream_t stream) {
    (void)in_sizes; (void)n_in; (void)out_size; (void)ws_size;
    const float* x     = (const float*)d_in[0];
    const float* w_qkv = (const float*)d_in[1];
    const float* w_out = (const float*)d_in[2];
    const float* b_out = (const float*)d_in[3];
    float* out = (float*)d_out;
    float* ws  = (float*)d_ws;    // needs 4*QSZ*4 = 64 MB

    qkv_kernel<<<dim3(S / 64, O3 / 64, B), 256, 0, stream>>>(x, w_qkv, ws);
    attn_kernel<<<dim3(S / 64, H, B), 256, 0, stream>>>(ws);
    oproj_kernel<<<dim3(S / 64, C / 64, B), 256, 0, stream>>>(ws, w_out, b_out, out);
}

// Round 3
// 921.003 us; speedup vs baseline: 2.3217x; 2.3217x over previous
//
#include <hip/hip_runtime.h>
#include <hip/hip_bf16.h>

// Problem constants
#define B 2
#define C 512
#define H 8
#define D 64
#define S 4096           // 64*64 tokens
#define O3 1536          // 3*C
#define SCALE 0.125f     // D^-0.5
#define E2 0.18033688011112042f   // SCALE * log2(e)

// Workspace layout:
//   q  : bf16 [B][H][S][D] @ 0                 (QSZ elems)
//   k  : bf16 [B][H][S][D] @ QSZ
//   v  : bf16 [B][H][D][S] @ 2*QSZ  (TRANSPOSED: d-major for PV B-frags)
//   ao : f32  [B][H][S][D] @ byte offset 3*QSZ*2  (= float offset AO_OFF_F32)
#define QSZ (B * H * S * D)            // 4,194,304
#define AO_OFF_F32 ((3 * QSZ) / 2)     // 6,291,456 floats

typedef __attribute__((ext_vector_type(8))) short bf16x8;
typedef __attribute__((ext_vector_type(4))) float f32x4;

__device__ __forceinline__ ushort f2bf(float f) {
    __hip_bfloat16 h = __float2bfloat16(f);
    return *reinterpret_cast<ushort*>(&h);
}

// ---------------------------------------------------------------------------
// Kernel 1: QKV projection (fp32 GEMM), outputs bf16 q/k (row-major) and
// v (transposed, [d][s]) into head-major workspace.
// ---------------------------------------------------------------------------
__global__ __launch_bounds__(256) void qkv_kernel(const float* __restrict__ x,
                                                  const float* __restrict__ w,
                                                  ushort* __restrict__ ws) {
    const int m0 = blockIdx.x * 64;
    const int o0 = blockIdx.y * 64;
    const int b  = blockIdx.z;
    const int tid = threadIdx.x;
    const int tx = tid & 15, ty = tid >> 4;

    __shared__ float As[32][64];   // [kk][mm]
    __shared__ float Bs[64][36];   // [oo][kk]

    float acc[4][4] = {};          // [i: m][j: o]
    const float* xb = x + (size_t)b * C * S;

    for (int k0 = 0; k0 < C; k0 += 32) {
        #pragma unroll
        for (int i = 0; i < 2; ++i) {
            int f = tid + i * 256;
            int kk = f >> 4, mv = f & 15;
            *(float4*)&As[kk][mv * 4] =
                *(const float4*)&xb[(size_t)(k0 + kk) * S + m0 + mv * 4];
        }
        #pragma unroll
        for (int i = 0; i < 2; ++i) {
            int f = tid + i * 256;
            int oo = f >> 3, kv = f & 7;
            *(float4*)&Bs[oo][kv * 4] =
                *(const float4*)&w[(size_t)(o0 + oo) * C + k0 + kv * 4];
        }
        __syncthreads();
        #pragma unroll
        for (int kk4 = 0; kk4 < 8; ++kk4) {
            float4 b4[4];
            #pragma unroll
            for (int j = 0; j < 4; ++j) b4[j] = *(float4*)&Bs[tx * 4 + j][kk4 * 4];
            #pragma unroll
            for (int kkk = 0; kkk < 4; ++kkk) {
                float4 a4 = *(float4*)&As[kk4 * 4 + kkk][ty * 4];
                float av[4] = {a4.x, a4.y, a4.z, a4.w};
                #pragma unroll
                for (int i = 0; i < 4; ++i) {
                    #pragma unroll
                    for (int j = 0; j < 4; ++j)
                        acc[i][j] += av[i] * ((const float*)&b4[j])[kkk];
                }
            }
        }
        __syncthreads();
    }

    const int t = o0 >> 9;          // 0=q, 1=k, 2=v
    const int h = (o0 & 511) >> 6;  // head
    if (t < 2) {
        ushort* dst = ws + (size_t)t * QSZ + (size_t)(b * H + h) * S * D;
        #pragma unroll
        for (int i = 0; i < 4; ++i) {
            int m = m0 + ty * 4 + i;
            ushort4 val = {f2bf(acc[i][0]), f2bf(acc[i][1]),
                           f2bf(acc[i][2]), f2bf(acc[i][3])};
            *(ushort4*)&dst[(size_t)m * D + tx * 4] = val;
        }
    } else {
        // v: write transposed [d][s]
        ushort* dst = ws + 2 * (size_t)QSZ + (size_t)(b * H + h) * D * S;
        #pragma unroll
        for (int j = 0; j < 4; ++j) {
            int dd = tx * 4 + j;
            ushort4 val = {f2bf(acc[0][j]), f2bf(acc[1][j]),
                           f2bf(acc[2][j]), f2bf(acc[3][j])};
            *(ushort4*)&dst[(size_t)dd * S + m0 + ty * 4] = val;
        }
    }
}

// ---------------------------------------------------------------------------
// Kernel 2: bf16 MFMA flash attention.
// Grid (S/128, H, B), 256 threads = 4 waves. Wave owns 32 q-rows.
// KV tiles of 64 rows; K and V^T staged in LDS (pad 72: 2-way conflicts only).
// Online softmax in fp32; P staged per-wave in LDS as bf16 (PV A-operand).
// mfma_f32_16x16x32_bf16: A row=l&15,k=(l>>4)*8+j; B col=l&15,k=(l>>4)*8+j;
// C col=lane&15, row=(lane>>4)*4+reg  [guide §3, m89-verified].
// ---------------------------------------------------------------------------
__global__ __launch_bounds__(256) void attn_kernel(const ushort* __restrict__ wsb,
                                                   float* __restrict__ ao) {
    const int q0 = blockIdx.x * 128;
    const int h  = blockIdx.y;
    const int b  = blockIdx.z;
    const int tid = threadIdx.x;
    const int w   = tid >> 6;
    const int l   = tid & 63;
    const int l15 = l & 15, l4 = l >> 4;

    const size_t bh = (size_t)(b * H + h);
    const ushort* qg = wsb + bh * S * D;
    const ushort* kg = wsb + (size_t)QSZ + bh * S * D;
    const ushort* vg = wsb + 2 * (size_t)QSZ + bh * D * S;   // [D][S]
    float* og = ao + bh * S * D;

    __shared__ __align__(16) ushort Kt[64][72];   // [kv][d]
    __shared__ __align__(16) ushort Vt[64][72];   // [d][kv]
    __shared__ __align__(16) ushort Pt[128][72];  // [q][kv], per-wave rows

    // Q fragments, held in registers for the whole block
    bf16x8 a_q[2][2];
    #pragma unroll
    for (int rt = 0; rt < 2; ++rt) {
        int row = q0 + w * 32 + rt * 16 + l15;
        #pragma unroll
        for (int c = 0; c < 2; ++c)
            a_q[rt][c] = *(const bf16x8*)&qg[(size_t)row * D + c * 32 + l4 * 8];
    }

    f32x4 o_acc[2][4];
    float m_run[2][4], l_run[2][4];
    #pragma unroll
    for (int rt = 0; rt < 2; ++rt)
        #pragma unroll
        for (int r = 0; r < 4; ++r) {
            m_run[rt][r] = -1e30f; l_run[rt][r] = 0.f;
        }
    #pragma unroll
    for (int rt = 0; rt < 2; ++rt)
        #pragma unroll
        for (int dt = 0; dt < 4; ++dt)
            o_acc[rt][dt] = (f32x4){0.f, 0.f, 0.f, 0.f};

    const f32x4 zero4 = (f32x4){0.f, 0.f, 0.f, 0.f};

    for (int kt = 0; kt < S / 64; ++kt) {
        __syncthreads();   // previous iter done reading Kt/Vt
        #pragma unroll
        for (int p2 = 0; p2 < 2; ++p2) {
            int f = tid + p2 * 256;
            int row = f >> 3, ch = f & 7;
            *(bf16x8*)&Kt[row][ch * 8] =
                *(const bf16x8*)&kg[(size_t)(kt * 64 + row) * D + ch * 8];
            *(bf16x8*)&Vt[row][ch * 8] =
                *(const bf16x8*)&vg[(size_t)row * S + kt * 64 + ch * 8];
        }
        __syncthreads();

        // ---- S = Q K^T (raw dot; scale folded into exp2 args) ----
        f32x4 s[2][4];
        #pragma unroll
        for (int nt = 0; nt < 4; ++nt) {
            bf16x8 bk0 = *(const bf16x8*)&Kt[nt * 16 + l15][l4 * 8];
            bf16x8 bk1 = *(const bf16x8*)&Kt[nt * 16 + l15][32 + l4 * 8];
            #pragma unroll
            for (int rt = 0; rt < 2; ++rt) {
                f32x4 t = __builtin_amdgcn_mfma_f32_16x16x32_bf16(
                    a_q[rt][0], bk0, zero4, 0, 0, 0);
                s[rt][nt] = __builtin_amdgcn_mfma_f32_16x16x32_bf16(
                    a_q[rt][1], bk1, t, 0, 0, 0);
            }
        }

        // ---- online softmax (rows live across 16-lane groups) ----
        #pragma unroll
        for (int rt = 0; rt < 2; ++rt) {
            #pragma unroll
            for (int reg = 0; reg < 4; ++reg) {
                float mt = fmaxf(fmaxf(s[rt][0][reg], s[rt][1][reg]),
                                 fmaxf(s[rt][2][reg], s[rt][3][reg]));
                #pragma unroll
                for (int off = 1; off < 16; off <<= 1)
                    mt = fmaxf(mt, __shfl_xor(mt, off, 64));
                float mn = fmaxf(m_run[rt][reg], mt);
                float alpha = __builtin_amdgcn_exp2f((m_run[rt][reg] - mn) * E2);
                float msc = mn * E2;
                float p[4], lt = 0.f;
                #pragma unroll
                for (int nt = 0; nt < 4; ++nt) {
                    p[nt] = __builtin_amdgcn_exp2f(fmaf(s[rt][nt][reg], E2, -msc));
                    lt += p[nt];
                }
                #pragma unroll
                for (int off = 1; off < 16; off <<= 1)
                    lt += __shfl_xor(lt, off, 64);
                l_run[rt][reg] = l_run[rt][reg] * alpha + lt;
                m_run[rt][reg] = mn;
                #pragma unroll
                for (int dt = 0; dt < 4; ++dt)
                    o_acc[rt][dt][reg] *= alpha;
                #pragma unroll
                for (int nt = 0; nt < 4; ++nt)
                    Pt[w * 32 + rt * 16 + l4 * 4 + reg][nt * 16 + l15] = f2bf(p[nt]);
            }
        }
        // Pt rows are per-wave private: same-wave DS ops are processed in
        // order; compiler inserts lgkmcnt for the RAW dependency.

        // ---- O += P V ----
        #pragma unroll
        for (int c = 0; c < 2; ++c) {
            bf16x8 ap0 = *(const bf16x8*)&Pt[w * 32 + l15][c * 32 + l4 * 8];
            bf16x8 ap1 = *(const bf16x8*)&Pt[w * 32 + 16 + l15][c * 32 + l4 * 8];
            #pragma unroll
            for (int dt = 0; dt < 4; ++dt) {
                bf16x8 bv = *(const bf16x8*)&Vt[dt * 16 + l15][c * 32 + l4 * 8];
                o_acc[0][dt] = __builtin_amdgcn_mfma_f32_16x16x32_bf16(
                    ap0, bv, o_acc[0][dt], 0, 0, 0);
                o_acc[1][dt] = __builtin_amdgcn_mfma_f32_16x16x32_bf16(
                    ap1, bv, o_acc[1][dt], 0, 0, 0);
            }
        }
    }

    // ---- epilogue: normalize, store fp32 ao ----
    #pragma unroll
    for (int rt = 0; rt < 2; ++rt) {
        #pragma unroll
        for (int reg = 0; reg < 4; ++reg) {
            float inv = 1.0f / l_run[rt][reg];
            int row = q0 + w * 32 + rt * 16 + l4 * 4 + reg;
            #pragma unroll
            for (int dt = 0; dt < 4; ++dt)
                og[(size_t)row * D + dt * 16 + l15] = o_acc[rt][dt][reg] * inv;
        }
    }
}

// ---------------------------------------------------------------------------
// Kernel 3: output projection + bias (fp32), writes transposed to [b][c][s].
// ---------------------------------------------------------------------------
__global__ __launch_bounds__(256) void oproj_kernel(const float* __restrict__ ws,
                                                    const float* __restrict__ w_out,
                                                    const float* __restrict__ b_out,
                                                    float* __restrict__ out) {
    const int m0 = blockIdx.x * 64;
    const int c0 = blockIdx.y * 64;
    const int b  = blockIdx.z;
    const int tid = threadIdx.x;
    const int tx = tid & 15, ty = tid >> 4;
    const float* ao = ws + (size_t)AO_OFF_F32 + (size_t)b * H * S * D;

    __shared__ float As[64][36];   // [mm][kk]
    __shared__ float Bs[64][36];   // [cc][kk]

    float acc[4][4] = {};          // [i: cc][j: m]

    for (int k0 = 0; k0 < C; k0 += 32) {
        const int hh = k0 >> 6, dd0 = k0 & 63;
        const float* ab = ao + (size_t)hh * S * D + dd0;
        #pragma unroll
        for (int i = 0; i < 2; ++i) {
            int f = tid + i * 256;
            int mm = f >> 3, kv = f & 7;
            *(float4*)&As[mm][kv * 4] =
                *(const float4*)&ab[(size_t)(m0 + mm) * D + kv * 4];
            *(float4*)&Bs[mm][kv * 4] =
                *(const float4*)&w_out[(size_t)(c0 + mm) * C + k0 + kv * 4];
        }
        __syncthreads();
        #pragma unroll
        for (int kk4 = 0; kk4 < 8; ++kk4) {
            float4 a4[4], b4[4];
            #pragma unroll
            for (int j = 0; j < 4; ++j) a4[j] = *(float4*)&As[tx * 4 + j][kk4 * 4];
            #pragma unroll
            for (int i = 0; i < 4; ++i) b4[i] = *(float4*)&Bs[ty * 4 + i][kk4 * 4];
            #pragma unroll
            for (int i = 0; i < 4; ++i) {
                #pragma unroll
                for (int j = 0; j < 4; ++j) {
                    acc[i][j] += a4[j].x * b4[i].x + a4[j].y * b4[i].y +
                                 a4[j].z * b4[i].z + a4[j].w * b4[i].w;
                }
            }
        }
        __syncthreads();
    }

    #pragma unroll
    for (int i = 0; i < 4; ++i) {
        int cc = c0 + ty * 4 + i;
        float bias = b_out[cc];
        float4 val = {acc[i][0] + bias, acc[i][1] + bias,
                      acc[i][2] + bias, acc[i][3] + bias};
        *(float4*)&out[(size_t)b * C * S + (size_t)cc * S + m0 + tx * 4] = val;
    }
}

// ---------------------------------------------------------------------------
extern "C" void kernel_launch(void* const* d_in, const int* in_sizes, int n_in,
                              void* d_out, int out_size, void* d_ws, size_t ws_size,
                              hipStream_t stream) {
    (void)in_sizes; (void)n_in; (void)out_size; (void)ws_size;
    const float* x     = (const float*)d_in[0];
    const float* w_qkv = (const float*)d_in[1];
    const float* w_out = (const float*)d_in[2];
    const float* b_out = (const float*)d_in[3];
    float* out = (float*)d_out;
    float* wsf = (float*)d_ws;
    ushort* wsb = (ushort*)d_ws;    // bf16 q/k/v arrays at front (ws >= 42 MB)

    qkv_kernel<<<dim3(S / 64, O3 / 64, B), 256, 0, stream>>>(x, w_qkv, wsb);
    attn_kernel<<<dim3(S / 128, H, B), 256, 0, stream>>>(wsb, wsf + AO_OFF_F32);
    oproj_kernel<<<dim3(S / 64, C / 64, B), 256, 0, stream>>>(wsf, w_out, b_out, out);
}

// Round 4
// 316.903 us; speedup vs baseline: 6.7474x; 2.9063x over previous
//
#include <hip/hip_runtime.h>
#include <hip/hip_bf16.h>

// Problem constants
#define B 2
#define C 512
#define H 8
#define D 64
#define S 4096           // 64*64 tokens
#define O3 1536          // 3*C
#define E2 0.18033688011112042f   // SCALE * log2(e),  SCALE = D^-0.5 = 0.125

// Workspace layout (ushort offsets; total 22,020,096 ushorts = 44 MB):
//   xT : bf16 [B][S][C]    @ XT_OFF   (x transposed, k-contiguous)
//   wq : bf16 [O3][C]      @ WQ_OFF
//   wo : bf16 [C][C]       @ WO_OFF
//   q  : bf16 [B][H][S][D] @ Q_OFF
//   k  : bf16 [B][H][S][D] @ K_OFF
//   v  : bf16 [B][H][D][S] @ V_OFF    (transposed: d-major for PV B-frags)
//   ao : bf16 [B][S][C]    @ AO_OFF   (attention out, channel-contiguous)
#define XT_OFF 0ull
#define WQ_OFF 4194304ull
#define WO_OFF 4980736ull
#define Q_OFF  5242880ull
#define K_OFF  9437184ull
#define V_OFF  13631488ull
#define AO_OFF 17825792ull

typedef __attribute__((ext_vector_type(8))) short bf16x8;
typedef __attribute__((ext_vector_type(4))) float f32x4;

__device__ __forceinline__ ushort f2bf(float f) {
    __hip_bfloat16 h = __float2bfloat16(f);
    return *reinterpret_cast<ushort*>(&h);
}

// ---------------------------------------------------------------------------
// Prep 1: transpose x [b][c][s] fp32 -> xT [b][s][c] bf16 via LDS tile.
// ---------------------------------------------------------------------------
__global__ __launch_bounds__(256) void transpose_x(const float* __restrict__ x,
                                                   ushort* __restrict__ xT) {
    const int s0 = blockIdx.x * 64, c0 = blockIdx.y * 64, b = blockIdx.z;
    const int tid = threadIdx.x;
    __shared__ float T[64][68];     // [c][s], pad 68 (stride 4 banks/row)

    const float* xb = x + (size_t)b * C * S;
    #pragma unroll
    for (int i = 0; i < 4; ++i) {
        int idx = tid + i * 256;
        int row = idx >> 4, sv = idx & 15;
        *(float4*)&T[row][sv * 4] =
            *(const float4*)&xb[(size_t)(c0 + row) * S + s0 + sv * 4];
    }
    __syncthreads();
    #pragma unroll
    for (int i = 0; i < 2; ++i) {
        int idx = tid + i * 256;
        int orow = idx >> 3, och = idx & 7;
        ushort tmp[8];
        #pragma unroll
        for (int j = 0; j < 8; ++j) tmp[j] = f2bf(T[och * 8 + j][orow]);
        ushort* dst = &xT[((size_t)b * S + s0 + orow) * C + c0 + och * 8];
        *(ushort4*)&dst[0] = *(ushort4*)&tmp[0];
        *(ushort4*)&dst[4] = *(ushort4*)&tmp[4];
    }
}

// ---------------------------------------------------------------------------
// Prep 2: fp32 -> bf16 elementwise (weights).
// ---------------------------------------------------------------------------
__global__ __launch_bounds__(256) void conv_bf16(const float* __restrict__ src,
                                                 ushort* __restrict__ dst, int n4) {
    int idx = blockIdx.x * 256 + threadIdx.x;
    if (idx < n4) {
        float4 v = *(const float4*)&src[(size_t)idx * 4];
        ushort4 o = {f2bf(v.x), f2bf(v.y), f2bf(v.z), f2bf(v.w)};
        *(ushort4*)&dst[(size_t)idx * 4] = o;
    }
}

// ---------------------------------------------------------------------------
// Kernel: QKV projection, bf16 MFMA.
// D[m][o] = sum_k xT[b][m][k] * wq[o][k].  M=4096, N=1536, K=512.
// 128x128 tile, BK=64, 4 waves (2x2), 4x4 fragments/wave.
// LDS pad 72: bank group = 4*(row+l4) mod 32 -> exactly 8 lanes/group per
// b128 access = wave64 minimum -> conflict-free reads and writes.
// ---------------------------------------------------------------------------
__global__ __launch_bounds__(256) void qkv_mfma(const ushort* __restrict__ xT,
                                                const ushort* __restrict__ wq,
                                                ushort* __restrict__ ws) {
    const int m0 = blockIdx.x * 128;
    const int o0 = blockIdx.y * 128;
    const int b  = blockIdx.z;
    const int tid = threadIdx.x;
    const int w = tid >> 6, l = tid & 63;
    const int l15 = l & 15, l4 = l >> 4;
    const int wr = w >> 1, wc = w & 1;

    __shared__ __align__(16) ushort At[128][72];
    __shared__ __align__(16) ushort Bt[128][72];

    const ushort* Ag = xT + ((size_t)b * S + m0) * C;
    const ushort* Bg = wq + (size_t)o0 * C;

    f32x4 acc[4][4];
    #pragma unroll
    for (int i = 0; i < 4; ++i)
        #pragma unroll
        for (int j = 0; j < 4; ++j) acc[i][j] = (f32x4){0.f, 0.f, 0.f, 0.f};

    for (int k0 = 0; k0 < C; k0 += 64) {
        if (k0) __syncthreads();
        #pragma unroll
        for (int i = 0; i < 4; ++i) {
            int idx = tid + i * 256;
            int row = idx >> 3, ch = idx & 7;
            *(bf16x8*)&At[row][ch * 8] =
                *(const bf16x8*)&Ag[(size_t)row * C + k0 + ch * 8];
            *(bf16x8*)&Bt[row][ch * 8] =
                *(const bf16x8*)&Bg[(size_t)row * C + k0 + ch * 8];
        }
        __syncthreads();
        #pragma unroll
        for (int c = 0; c < 2; ++c) {
            bf16x8 af[4], bfr[4];
            #pragma unroll
            for (int i = 0; i < 4; ++i) {
                af[i]  = *(const bf16x8*)&At[wr * 64 + i * 16 + l15][c * 32 + l4 * 8];
                bfr[i] = *(const bf16x8*)&Bt[wc * 64 + i * 16 + l15][c * 32 + l4 * 8];
            }
            #pragma unroll
            for (int i = 0; i < 4; ++i)
                #pragma unroll
                for (int j = 0; j < 4; ++j)
                    acc[i][j] = __builtin_amdgcn_mfma_f32_16x16x32_bf16(
                        af[i], bfr[j], acc[i][j], 0, 0, 0);
        }
    }

    // Epilogue: C frag col = l15 (o dim), row = l4*4+r (m dim).
    const int t = o0 >> 9;          // 0=q, 1=k, 2=v (128-tiles align to 512)
    #pragma unroll
    for (int j = 0; j < 4; ++j) {
        const int ob = o0 + wc * 64 + j * 16;
        const int h  = (ob & 511) >> 6;
        const int d0 = (ob & 63) + l15;
        if (t < 2) {
            ushort* dst = ws + (t == 0 ? Q_OFF : K_OFF) + (size_t)(b * H + h) * S * D;
            #pragma unroll
            for (int i = 0; i < 4; ++i) {
                #pragma unroll
                for (int r = 0; r < 4; ++r) {
                    int m = m0 + wr * 64 + i * 16 + l4 * 4 + r;
                    dst[(size_t)m * D + d0] = f2bf(acc[i][j][r]);
                }
            }
        } else {
            ushort* dst = ws + V_OFF + (size_t)(b * H + h) * D * S + (size_t)d0 * S;
            #pragma unroll
            for (int i = 0; i < 4; ++i) {
                int m = m0 + wr * 64 + i * 16 + l4 * 4;
                ushort4 pk = {f2bf(acc[i][j][0]), f2bf(acc[i][j][1]),
                              f2bf(acc[i][j][2]), f2bf(acc[i][j][3])};
                *(ushort4*)&dst[m] = pk;
            }
        }
    }
}

// ---------------------------------------------------------------------------
// Kernel: bf16 MFMA flash attention (unchanged math from R3; new pointers,
// epilogue now writes bf16 ao[b][s][c] directly).
// ---------------------------------------------------------------------------
__global__ __launch_bounds__(256) void attn_kernel(const ushort* __restrict__ wsb,
                                                   ushort* __restrict__ aob) {
    const int q0 = blockIdx.x * 128;
    const int h  = blockIdx.y;
    const int b  = blockIdx.z;
    const int tid = threadIdx.x;
    const int w   = tid >> 6;
    const int l   = tid & 63;
    const int l15 = l & 15, l4 = l >> 4;

    const size_t bh = (size_t)(b * H + h);
    const ushort* qg = wsb + Q_OFF + bh * S * D;
    const ushort* kg = wsb + K_OFF + bh * S * D;
    const ushort* vg = wsb + V_OFF + bh * D * S;   // [D][S]

    __shared__ __align__(16) ushort Kt[64][72];   // [kv][d]
    __shared__ __align__(16) ushort Vt[64][72];   // [d][kv]
    __shared__ __align__(16) ushort Pt[128][72];  // [q][kv], per-wave rows

    bf16x8 a_q[2][2];
    #pragma unroll
    for (int rt = 0; rt < 2; ++rt) {
        int row = q0 + w * 32 + rt * 16 + l15;
        #pragma unroll
        for (int c = 0; c < 2; ++c)
            a_q[rt][c] = *(const bf16x8*)&qg[(size_t)row * D + c * 32 + l4 * 8];
    }

    f32x4 o_acc[2][4];
    float m_run[2][4], l_run[2][4];
    #pragma unroll
    for (int rt = 0; rt < 2; ++rt)
        #pragma unroll
        for (int r = 0; r < 4; ++r) {
            m_run[rt][r] = -1e30f; l_run[rt][r] = 0.f;
        }
    #pragma unroll
    for (int rt = 0; rt < 2; ++rt)
        #pragma unroll
        for (int dt = 0; dt < 4; ++dt)
            o_acc[rt][dt] = (f32x4){0.f, 0.f, 0.f, 0.f};

    const f32x4 zero4 = (f32x4){0.f, 0.f, 0.f, 0.f};

    for (int kt = 0; kt < S / 64; ++kt) {
        __syncthreads();
        #pragma unroll
        for (int p2 = 0; p2 < 2; ++p2) {
            int f = tid + p2 * 256;
            int row = f >> 3, ch = f & 7;
            *(bf16x8*)&Kt[row][ch * 8] =
                *(const bf16x8*)&kg[(size_t)(kt * 64 + row) * D + ch * 8];
            *(bf16x8*)&Vt[row][ch * 8] =
                *(const bf16x8*)&vg[(size_t)row * S + kt * 64 + ch * 8];
        }
        __syncthreads();

        // ---- S = Q K^T ----
        f32x4 s[2][4];
        #pragma unroll
        for (int nt = 0; nt < 4; ++nt) {
            bf16x8 bk0 = *(const bf16x8*)&Kt[nt * 16 + l15][l4 * 8];
            bf16x8 bk1 = *(const bf16x8*)&Kt[nt * 16 + l15][32 + l4 * 8];
            #pragma unroll
            for (int rt = 0; rt < 2; ++rt) {
                f32x4 t = __builtin_amdgcn_mfma_f32_16x16x32_bf16(
                    a_q[rt][0], bk0, zero4, 0, 0, 0);
                s[rt][nt] = __builtin_amdgcn_mfma_f32_16x16x32_bf16(
                    a_q[rt][1], bk1, t, 0, 0, 0);
            }
        }

        // ---- online softmax ----
        #pragma unroll
        for (int rt = 0; rt < 2; ++rt) {
            #pragma unroll
            for (int reg = 0; reg < 4; ++reg) {
                float mt = fmaxf(fmaxf(s[rt][0][reg], s[rt][1][reg]),
                                 fmaxf(s[rt][2][reg], s[rt][3][reg]));
                #pragma unroll
                for (int off = 1; off < 16; off <<= 1)
                    mt = fmaxf(mt, __shfl_xor(mt, off, 64));
                float mn = fmaxf(m_run[rt][reg], mt);
                float alpha = __builtin_amdgcn_exp2f((m_run[rt][reg] - mn) * E2);
                float msc = mn * E2;
                float p[4], lt = 0.f;
                #pragma unroll
                for (int nt = 0; nt < 4; ++nt) {
                    p[nt] = __builtin_amdgcn_exp2f(fmaf(s[rt][nt][reg], E2, -msc));
                    lt += p[nt];
                }
                #pragma unroll
                for (int off = 1; off < 16; off <<= 1)
                    lt += __shfl_xor(lt, off, 64);
                l_run[rt][reg] = l_run[rt][reg] * alpha + lt;
                m_run[rt][reg] = mn;
                #pragma unroll
                for (int dt = 0; dt < 4; ++dt)
                    o_acc[rt][dt][reg] *= alpha;
                #pragma unroll
                for (int nt = 0; nt < 4; ++nt)
                    Pt[w * 32 + rt * 16 + l4 * 4 + reg][nt * 16 + l15] = f2bf(p[nt]);
            }
        }

        // ---- O += P V ----
        #pragma unroll
        for (int c = 0; c < 2; ++c) {
            bf16x8 ap0 = *(const bf16x8*)&Pt[w * 32 + l15][c * 32 + l4 * 8];
            bf16x8 ap1 = *(const bf16x8*)&Pt[w * 32 + 16 + l15][c * 32 + l4 * 8];
            #pragma unroll
            for (int dt = 0; dt < 4; ++dt) {
                bf16x8 bv = *(const bf16x8*)&Vt[dt * 16 + l15][c * 32 + l4 * 8];
                o_acc[0][dt] = __builtin_amdgcn_mfma_f32_16x16x32_bf16(
                    ap0, bv, o_acc[0][dt], 0, 0, 0);
                o_acc[1][dt] = __builtin_amdgcn_mfma_f32_16x16x32_bf16(
                    ap1, bv, o_acc[1][dt], 0, 0, 0);
            }
        }
    }

    // ---- epilogue: normalize, store bf16 ao[b][s][c] ----
    #pragma unroll
    for (int rt = 0; rt < 2; ++rt) {
        #pragma unroll
        for (int reg = 0; reg < 4; ++reg) {
            float inv = 1.0f / l_run[rt][reg];
            int row = q0 + w * 32 + rt * 16 + l4 * 4 + reg;
            #pragma unroll
            for (int dt = 0; dt < 4; ++dt)
                aob[((size_t)b * S + row) * C + h * 64 + dt * 16 + l15] =
                    f2bf(o_acc[rt][dt][reg] * inv);
        }
    }
}

// ---------------------------------------------------------------------------
// Kernel: output projection, bf16 MFMA, + bias, fp32 out [b][c][s].
// D[cc][m] = sum_k wo[cc][k] * ao[b][m][k].  M=512, N=4096, K=512.
// ---------------------------------------------------------------------------
__global__ __launch_bounds__(256) void oproj_mfma(const ushort* __restrict__ wo,
                                                  const ushort* __restrict__ aob,
                                                  const float* __restrict__ b_out,
                                                  float* __restrict__ out) {
    const int cc0 = blockIdx.x * 128;
    const int n0  = blockIdx.y * 128;
    const int b   = blockIdx.z;
    const int tid = threadIdx.x;
    const int w = tid >> 6, l = tid & 63;
    const int l15 = l & 15, l4 = l >> 4;
    const int wr = w >> 1, wc = w & 1;

    __shared__ __align__(16) ushort At[128][72];
    __shared__ __align__(16) ushort Bt[128][72];

    const ushort* Ag = wo + (size_t)cc0 * C;
    const ushort* Bg = aob + ((size_t)b * S + n0) * C;

    f32x4 acc[4][4];
    #pragma unroll
    for (int i = 0; i < 4; ++i)
        #pragma unroll
        for (int j = 0; j < 4; ++j) acc[i][j] = (f32x4){0.f, 0.f, 0.f, 0.f};

    for (int k0 = 0; k0 < C; k0 += 64) {
        if (k0) __syncthreads();
        #pragma unroll
        for (int i = 0; i < 4; ++i) {
            int idx = tid + i * 256;
            int row = idx >> 3, ch = idx & 7;
            *(bf16x8*)&At[row][ch * 8] =
                *(const bf16x8*)&Ag[(size_t)row * C + k0 + ch * 8];
            *(bf16x8*)&Bt[row][ch * 8] =
                *(const bf16x8*)&Bg[(size_t)row * C + k0 + ch * 8];
        }
        __syncthreads();
        #pragma unroll
        for (int c = 0; c < 2; ++c) {
            bf16x8 af[4], bfr[4];
            #pragma unroll
            for (int i = 0; i < 4; ++i) {
                af[i]  = *(const bf16x8*)&At[wr * 64 + i * 16 + l15][c * 32 + l4 * 8];
                bfr[i] = *(const bf16x8*)&Bt[wc * 64 + i * 16 + l15][c * 32 + l4 * 8];
            }
            #pragma unroll
            for (int i = 0; i < 4; ++i)
                #pragma unroll
                for (int j = 0; j < 4; ++j)
                    acc[i][j] = __builtin_amdgcn_mfma_f32_16x16x32_bf16(
                        af[i], bfr[j], acc[i][j], 0, 0, 0);
        }
    }

    #pragma unroll
    for (int i = 0; i < 4; ++i) {
        #pragma unroll
        for (int r = 0; r < 4; ++r) {
            int cc = cc0 + wr * 64 + i * 16 + l4 * 4 + r;
            float bias = b_out[cc];
            #pragma unroll
            for (int j = 0; j < 4; ++j) {
                int mm = n0 + wc * 64 + j * 16 + l15;
                out[((size_t)b * C + cc) * S + mm] = acc[i][j][r] + bias;
            }
        }
    }
}

// ---------------------------------------------------------------------------
extern "C" void kernel_launch(void* const* d_in, const int* in_sizes, int n_in,
                              void* d_out, int out_size, void* d_ws, size_t ws_size,
                              hipStream_t stream) {
    (void)in_sizes; (void)n_in; (void)out_size; (void)ws_size;
    const float* x     = (const float*)d_in[0];
    const float* w_qkv = (const float*)d_in[1];
    const float* w_out = (const float*)d_in[2];
    const float* b_out = (const float*)d_in[3];
    float* out = (float*)d_out;
    ushort* wsb = (ushort*)d_ws;    // 44 MB used

    transpose_x<<<dim3(S / 64, C / 64, B), 256, 0, stream>>>(x, wsb + XT_OFF);
    conv_bf16<<<dim3((O3 * C / 4 + 255) / 256), 256, 0, stream>>>(w_qkv, wsb + WQ_OFF, O3 * C / 4);
    conv_bf16<<<dim3((C * C / 4 + 255) / 256), 256, 0, stream>>>(w_out, wsb + WO_OFF, C * C / 4);
    qkv_mfma<<<dim3(S / 128, O3 / 128, B), 256, 0, stream>>>(wsb + XT_OFF, wsb + WQ_OFF, wsb);
    attn_kernel<<<dim3(S / 128, H, B), 256, 0, stream>>>(wsb, wsb + AO_OFF);
    oproj_mfma<<<dim3(C / 128, S / 128, B), 256, 0, stream>>>(wsb + WO_OFF, wsb + AO_OFF, b_out, out);
}

// Round 5
// 278.364 us; speedup vs baseline: 7.6816x; 1.1385x over previous
//
#include <hip/hip_runtime.h>
#include <hip/hip_bf16.h>

// Problem constants
#define B 2
#define C 512
#define H 8
#define D 64
#define S 4096           // 64*64 tokens
#define O3 1536          // 3*C
#define E2 0.18033688011112042f   // SCALE * log2(e),  SCALE = D^-0.5 = 0.125
#define THR_RAW 64.0f    // defer-max threshold: 8 nats / SCALE

// Workspace layout (ushort offsets; total 22,020,096 ushorts = 44 MB):
//   xT : bf16 [B][S][C]    @ XT_OFF   (x transposed, k-contiguous)
//   wq : bf16 [O3][C]      @ WQ_OFF
//   wo : bf16 [C][C]       @ WO_OFF
//   q  : bf16 [B][H][S][D] @ Q_OFF
//   k  : bf16 [B][H][S][D] @ K_OFF
//   v  : bf16 [B][H][D][S] @ V_OFF    (transposed: d-major for PV B-frags)
//   ao : bf16 [B][S][C]    @ AO_OFF   (attention out, channel-contiguous)
#define XT_OFF 0ull
#define WQ_OFF 4194304ull
#define WO_OFF 4980736ull
#define Q_OFF  5242880ull
#define K_OFF  9437184ull
#define V_OFF  13631488ull
#define AO_OFF 17825792ull

typedef __attribute__((ext_vector_type(8))) short bf16x8;
typedef __attribute__((ext_vector_type(4))) float f32x4;

__device__ __forceinline__ ushort f2bf(float f) {
    __hip_bfloat16 h = __float2bfloat16(f);
    return *reinterpret_cast<ushort*>(&h);
}

// ---------------------------------------------------------------------------
// Prep 1: transpose x [b][c][s] fp32 -> xT [b][s][c] bf16 via LDS tile.
// ---------------------------------------------------------------------------
__global__ __launch_bounds__(256) void transpose_x(const float* __restrict__ x,
                                                   ushort* __restrict__ xT) {
    const int s0 = blockIdx.x * 64, c0 = blockIdx.y * 64, b = blockIdx.z;
    const int tid = threadIdx.x;
    __shared__ float T[64][68];

    const float* xb = x + (size_t)b * C * S;
    #pragma unroll
    for (int i = 0; i < 4; ++i) {
        int idx = tid + i * 256;
        int row = idx >> 4, sv = idx & 15;
        *(float4*)&T[row][sv * 4] =
            *(const float4*)&xb[(size_t)(c0 + row) * S + s0 + sv * 4];
    }
    __syncthreads();
    #pragma unroll
    for (int i = 0; i < 2; ++i) {
        int idx = tid + i * 256;
        int orow = idx >> 3, och = idx & 7;
        ushort tmp[8];
        #pragma unroll
        for (int j = 0; j < 8; ++j) tmp[j] = f2bf(T[och * 8 + j][orow]);
        ushort* dst = &xT[((size_t)b * S + s0 + orow) * C + c0 + och * 8];
        *(ushort4*)&dst[0] = *(ushort4*)&tmp[0];
        *(ushort4*)&dst[4] = *(ushort4*)&tmp[4];
    }
}

// ---------------------------------------------------------------------------
// Prep 2: fp32 -> bf16 elementwise (weights).
// ---------------------------------------------------------------------------
__global__ __launch_bounds__(256) void conv_bf16(const float* __restrict__ src,
                                                 ushort* __restrict__ dst, int n4) {
    int idx = blockIdx.x * 256 + threadIdx.x;
    if (idx < n4) {
        float4 v = *(const float4*)&src[(size_t)idx * 4];
        ushort4 o = {f2bf(v.x), f2bf(v.y), f2bf(v.z), f2bf(v.w)};
        *(ushort4*)&dst[(size_t)idx * 4] = o;
    }
}

// ---------------------------------------------------------------------------
// Kernel: QKV projection, bf16 MFMA (unchanged from R4).
// ---------------------------------------------------------------------------
__global__ __launch_bounds__(256) void qkv_mfma(const ushort* __restrict__ xT,
                                                const ushort* __restrict__ wq,
                                                ushort* __restrict__ ws) {
    const int m0 = blockIdx.x * 128;
    const int o0 = blockIdx.y * 128;
    const int b  = blockIdx.z;
    const int tid = threadIdx.x;
    const int w = tid >> 6, l = tid & 63;
    const int l15 = l & 15, l4 = l >> 4;
    const int wr = w >> 1, wc = w & 1;

    __shared__ __align__(16) ushort At[128][72];
    __shared__ __align__(16) ushort Bt[128][72];

    const ushort* Ag = xT + ((size_t)b * S + m0) * C;
    const ushort* Bg = wq + (size_t)o0 * C;

    f32x4 acc[4][4];
    #pragma unroll
    for (int i = 0; i < 4; ++i)
        #pragma unroll
        for (int j = 0; j < 4; ++j) acc[i][j] = (f32x4){0.f, 0.f, 0.f, 0.f};

    for (int k0 = 0; k0 < C; k0 += 64) {
        if (k0) __syncthreads();
        #pragma unroll
        for (int i = 0; i < 4; ++i) {
            int idx = tid + i * 256;
            int row = idx >> 3, ch = idx & 7;
            *(bf16x8*)&At[row][ch * 8] =
                *(const bf16x8*)&Ag[(size_t)row * C + k0 + ch * 8];
            *(bf16x8*)&Bt[row][ch * 8] =
                *(const bf16x8*)&Bg[(size_t)row * C + k0 + ch * 8];
        }
        __syncthreads();
        #pragma unroll
        for (int c = 0; c < 2; ++c) {
            bf16x8 af[4], bfr[4];
            #pragma unroll
            for (int i = 0; i < 4; ++i) {
                af[i]  = *(const bf16x8*)&At[wr * 64 + i * 16 + l15][c * 32 + l4 * 8];
                bfr[i] = *(const bf16x8*)&Bt[wc * 64 + i * 16 + l15][c * 32 + l4 * 8];
            }
            #pragma unroll
            for (int i = 0; i < 4; ++i)
                #pragma unroll
                for (int j = 0; j < 4; ++j)
                    acc[i][j] = __builtin_amdgcn_mfma_f32_16x16x32_bf16(
                        af[i], bfr[j], acc[i][j], 0, 0, 0);
        }
    }

    const int t = o0 >> 9;
    #pragma unroll
    for (int j = 0; j < 4; ++j) {
        const int ob = o0 + wc * 64 + j * 16;
        const int h  = (ob & 511) >> 6;
        const int d0 = (ob & 63) + l15;
        if (t < 2) {
            ushort* dst = ws + (t == 0 ? Q_OFF : K_OFF) + (size_t)(b * H + h) * S * D;
            #pragma unroll
            for (int i = 0; i < 4; ++i) {
                #pragma unroll
                for (int r = 0; r < 4; ++r) {
                    int m = m0 + wr * 64 + i * 16 + l4 * 4 + r;
                    dst[(size_t)m * D + d0] = f2bf(acc[i][j][r]);
                }
            }
        } else {
            ushort* dst = ws + V_OFF + (size_t)(b * H + h) * D * S + (size_t)d0 * S;
            #pragma unroll
            for (int i = 0; i < 4; ++i) {
                int m = m0 + wr * 64 + i * 16 + l4 * 4;
                ushort4 pk = {f2bf(acc[i][j][0]), f2bf(acc[i][j][1]),
                              f2bf(acc[i][j][2]), f2bf(acc[i][j][3])};
                *(ushort4*)&dst[m] = pk;
            }
        }
    }
}

// ---------------------------------------------------------------------------
// Kernel: bf16 MFMA flash attention, v2.
// QBLK=64 (grid 1024 blocks -> 4 blocks/CU, 16 waves/CU), wave owns 16 rows.
// Async-stage split (prefetch next K/V tile into regs under compute),
// row-sum via ones-column MFMA, defer-max rescale (THR=8 nats), setprio.
// ---------------------------------------------------------------------------
__global__ __launch_bounds__(256) void attn_kernel(const ushort* __restrict__ wsb,
                                                   ushort* __restrict__ aob) {
    const int q0 = blockIdx.x * 64;
    const int h  = blockIdx.y;
    const int b  = blockIdx.z;
    const int tid = threadIdx.x;
    const int w   = tid >> 6;
    const int l   = tid & 63;
    const int l15 = l & 15, l4 = l >> 4;

    const size_t bh = (size_t)(b * H + h);
    const ushort* qg = wsb + Q_OFF + bh * S * D;
    const ushort* kg = wsb + K_OFF + bh * S * D;
    const ushort* vg = wsb + V_OFF + bh * D * S;   // [D][S]

    __shared__ __align__(16) ushort Kt[64][72];   // [kv][d]
    __shared__ __align__(16) ushort Vt[64][72];   // [d][kv]
    __shared__ __align__(16) ushort Pt[64][72];   // [q][kv], per-wave rows

    // Q fragments for the whole block
    bf16x8 a_q[2];
    {
        int row = q0 + w * 16 + l15;
        a_q[0] = *(const bf16x8*)&qg[(size_t)row * D + l4 * 8];
        a_q[1] = *(const bf16x8*)&qg[(size_t)row * D + 32 + l4 * 8];
    }

    // o_acc[0..3] = d-columns; o_acc[4] = ones-column (row-sum / l accumulator)
    f32x4 o_acc[5];
    float m_run[4];
    #pragma unroll
    for (int dt = 0; dt < 5; ++dt) o_acc[dt] = (f32x4){0.f, 0.f, 0.f, 0.f};
    #pragma unroll
    for (int r = 0; r < 4; ++r) m_run[r] = -1e30f;

    const f32x4 zero4 = (f32x4){0.f, 0.f, 0.f, 0.f};
    const short one_bf = (short)0x3F80;
    const bf16x8 ones8 = {one_bf, one_bf, one_bf, one_bf,
                          one_bf, one_bf, one_bf, one_bf};

    // staging map: thread covers (row, ch) and (row+32, ch)
    const int srow = tid >> 3, sch = tid & 7;

    // prologue: stage tile 0 into regs
    bf16x8 kst[2], vst[2];
    #pragma unroll
    for (int p = 0; p < 2; ++p) {
        kst[p] = *(const bf16x8*)&kg[(size_t)(srow + p * 32) * D + sch * 8];
        vst[p] = *(const bf16x8*)&vg[(size_t)(srow + p * 32) * S + sch * 8];
    }

    const int NT = S / 64;
    for (int kt = 0; kt < NT; ++kt) {
        // write staged tile to LDS (vmcnt wait inserted by compiler)
        #pragma unroll
        for (int p = 0; p < 2; ++p) {
            *(bf16x8*)&Kt[srow + p * 32][sch * 8] = kst[p];
            *(bf16x8*)&Vt[srow + p * 32][sch * 8] = vst[p];
        }
        __syncthreads();

        // prefetch next tile into regs; latency hides under compute below
        if (kt + 1 < NT) {
            #pragma unroll
            for (int p = 0; p < 2; ++p) {
                kst[p] = *(const bf16x8*)&kg[(size_t)((kt + 1) * 64 + srow + p * 32) * D + sch * 8];
                vst[p] = *(const bf16x8*)&vg[(size_t)(srow + p * 32) * S + (kt + 1) * 64 + sch * 8];
            }
        }

        // ---- S = Q K^T ----
        f32x4 s[4];
        __builtin_amdgcn_s_setprio(1);
        #pragma unroll
        for (int nt = 0; nt < 4; ++nt) {
            bf16x8 bk0 = *(const bf16x8*)&Kt[nt * 16 + l15][l4 * 8];
            bf16x8 bk1 = *(const bf16x8*)&Kt[nt * 16 + l15][32 + l4 * 8];
            f32x4 t = __builtin_amdgcn_mfma_f32_16x16x32_bf16(a_q[0], bk0, zero4, 0, 0, 0);
            s[nt] = __builtin_amdgcn_mfma_f32_16x16x32_bf16(a_q[1], bk1, t, 0, 0, 0);
        }
        __builtin_amdgcn_s_setprio(0);

        // ---- tile max (16-lane shuffle reduce), defer-max rescale ----
        float mt[4];
        #pragma unroll
        for (int reg = 0; reg < 4; ++reg) {
            float m0 = fmaxf(fmaxf(s[0][reg], s[1][reg]),
                             fmaxf(s[2][reg], s[3][reg]));
            #pragma unroll
            for (int off = 1; off < 16; off <<= 1)
                m0 = fmaxf(m0, __shfl_xor(m0, off, 64));
            mt[reg] = m0;
        }
        bool ok = (mt[0] <= m_run[0] + THR_RAW) && (mt[1] <= m_run[1] + THR_RAW) &&
                  (mt[2] <= m_run[2] + THR_RAW) && (mt[3] <= m_run[3] + THR_RAW);
        if (!__all(ok)) {
            #pragma unroll
            for (int reg = 0; reg < 4; ++reg) {
                float mn = fmaxf(m_run[reg], mt[reg]);
                float alpha = __builtin_amdgcn_exp2f((m_run[reg] - mn) * E2);
                m_run[reg] = mn;
                #pragma unroll
                for (int dt = 0; dt < 5; ++dt) o_acc[dt][reg] *= alpha;
            }
        }

        // ---- P = exp(S - m), store bf16 to Pt (wave-private rows) ----
        #pragma unroll
        for (int reg = 0; reg < 4; ++reg) {
            float msc = m_run[reg] * E2;
            #pragma unroll
            for (int nt = 0; nt < 4; ++nt) {
                float p = __builtin_amdgcn_exp2f(fmaf(s[nt][reg], E2, -msc));
                Pt[w * 16 + l4 * 4 + reg][nt * 16 + l15] = f2bf(p);
            }
        }

        // ---- O += P V ; l += P @ ones ----
        __builtin_amdgcn_s_setprio(1);
        #pragma unroll
        for (int c = 0; c < 2; ++c) {
            bf16x8 ap = *(const bf16x8*)&Pt[w * 16 + l15][c * 32 + l4 * 8];
            #pragma unroll
            for (int dt = 0; dt < 4; ++dt) {
                bf16x8 bv = *(const bf16x8*)&Vt[dt * 16 + l15][c * 32 + l4 * 8];
                o_acc[dt] = __builtin_amdgcn_mfma_f32_16x16x32_bf16(
                    ap, bv, o_acc[dt], 0, 0, 0);
            }
            o_acc[4] = __builtin_amdgcn_mfma_f32_16x16x32_bf16(
                ap, ones8, o_acc[4], 0, 0, 0);
        }
        __builtin_amdgcn_s_setprio(0);
        __syncthreads();
    }

    // ---- epilogue: normalize, store bf16 ao[b][s][c] ----
    #pragma unroll
    for (int reg = 0; reg < 4; ++reg) {
        float inv = 1.0f / o_acc[4][reg];
        int row = q0 + w * 16 + l4 * 4 + reg;
        #pragma unroll
        for (int dt = 0; dt < 4; ++dt)
            aob[((size_t)b * S + row) * C + h * 64 + dt * 16 + l15] =
                f2bf(o_acc[dt][reg] * inv);
    }
}

// ---------------------------------------------------------------------------
// Kernel: output projection, bf16 MFMA, + bias, fp32 out [b][c][s]
// (unchanged from R4).
// ---------------------------------------------------------------------------
__global__ __launch_bounds__(256) void oproj_mfma(const ushort* __restrict__ wo,
                                                  const ushort* __restrict__ aob,
                                                  const float* __restrict__ b_out,
                                                  float* __restrict__ out) {
    const int cc0 = blockIdx.x * 128;
    const int n0  = blockIdx.y * 128;
    const int b   = blockIdx.z;
    const int tid = threadIdx.x;
    const int w = tid >> 6, l = tid & 63;
    const int l15 = l & 15, l4 = l >> 4;
    const int wr = w >> 1, wc = w & 1;

    __shared__ __align__(16) ushort At[128][72];
    __shared__ __align__(16) ushort Bt[128][72];

    const ushort* Ag = wo + (size_t)cc0 * C;
    const ushort* Bg = aob + ((size_t)b * S + n0) * C;

    f32x4 acc[4][4];
    #pragma unroll
    for (int i = 0; i < 4; ++i)
        #pragma unroll
        for (int j = 0; j < 4; ++j) acc[i][j] = (f32x4){0.f, 0.f, 0.f, 0.f};

    for (int k0 = 0; k0 < C; k0 += 64) {
        if (k0) __syncthreads();
        #pragma unroll
        for (int i = 0; i < 4; ++i) {
            int idx = tid + i * 256;
            int row = idx >> 3, ch = idx & 7;
            *(bf16x8*)&At[row][ch * 8] =
                *(const bf16x8*)&Ag[(size_t)row * C + k0 + ch * 8];
            *(bf16x8*)&Bt[row][ch * 8] =
                *(const bf16x8*)&Bg[(size_t)row * C + k0 + ch * 8];
        }
        __syncthreads();
        #pragma unroll
        for (int c = 0; c < 2; ++c) {
            bf16x8 af[4], bfr[4];
            #pragma unroll
            for (int i = 0; i < 4; ++i) {
                af[i]  = *(const bf16x8*)&At[wr * 64 + i * 16 + l15][c * 32 + l4 * 8];
                bfr[i] = *(const bf16x8*)&Bt[wc * 64 + i * 16 + l15][c * 32 + l4 * 8];
            }
            #pragma unroll
            for (int i = 0; i < 4; ++i)
                #pragma unroll
                for (int j = 0; j < 4; ++j)
                    acc[i][j] = __builtin_amdgcn_mfma_f32_16x16x32_bf16(
                        af[i], bfr[j], acc[i][j], 0, 0, 0);
        }
    }

    #pragma unroll
    for (int i = 0; i < 4; ++i) {
        #pragma unroll
        for (int r = 0; r < 4; ++r) {
            int cc = cc0 + wr * 64 + i * 16 + l4 * 4 + r;
            float bias = b_out[cc];
            #pragma unroll
            for (int j = 0; j < 4; ++j) {
                int mm = n0 + wc * 64 + j * 16 + l15;
                out[((size_t)b * C + cc) * S + mm] = acc[i][j][r] + bias;
            }
        }
    }
}

// ---------------------------------------------------------------------------
extern "C" void kernel_launch(void* const* d_in, const int* in_sizes, int n_in,
                              void* d_out, int out_size, void* d_ws, size_t ws_size,
                              hipStream_t stream) {
    (void)in_sizes; (void)n_in; (void)out_size; (void)ws_size;
    const float* x     = (const float*)d_in[0];
    const float* w_qkv = (const float*)d_in[1];
    const float* w_out = (const float*)d_in[2];
    const float* b_out = (const float*)d_in[3];
    float* out = (float*)d_out;
    ushort* wsb = (ushort*)d_ws;    // 44 MB used

    transpose_x<<<dim3(S / 64, C / 64, B), 256, 0, stream>>>(x, wsb + XT_OFF);
    conv_bf16<<<dim3((O3 * C / 4 + 255) / 256), 256, 0, stream>>>(w_qkv, wsb + WQ_OFF, O3 * C / 4);
    conv_bf16<<<dim3((C * C / 4 + 255) / 256), 256, 0, stream>>>(w_out, wsb + WO_OFF, C * C / 4);
    qkv_mfma<<<dim3(S / 128, O3 / 128, B), 256, 0, stream>>>(wsb + XT_OFF, wsb + WQ_OFF, wsb);
    attn_kernel<<<dim3(S / 64, H, B), 256, 0, stream>>>(wsb, wsb + AO_OFF);
    oproj_mfma<<<dim3(C / 128, S / 128, B), 256, 0, stream>>>(wsb + WO_OFF, wsb + AO_OFF, b_out, out);
}

// Round 6
// 195.227 us; speedup vs baseline: 10.9527x; 1.4258x over previous
//
#include <hip/hip_runtime.h>
#include <hip/hip_bf16.h>

// Problem constants
#define B 2
#define C 512
#define H 8
#define D 64
#define S 4096           // 64*64 tokens
#define O3 1536          // 3*C
#define E2 0.18033688011112042f   // SCALE * log2(e),  SCALE = D^-0.5 = 0.125
#define THR_RAW 64.0f    // defer-max threshold: 8 nats / SCALE

// Workspace layout (ushort offsets; total 22,020,096 ushorts = 44 MB):
//   xT : bf16 [B][S][C]    @ XT_OFF   (x transposed, k-contiguous)
//   wq : bf16 [O3][C]      @ WQ_OFF
//   wo : bf16 [C][C]       @ WO_OFF
//   q  : bf16 [B][H][S][D] @ Q_OFF
//   k  : bf16 [B][H][S][D] @ K_OFF
//   v  : bf16 [B][H][D][S] @ V_OFF    (transposed: d-major)
//   ao : bf16 [B][S][C]    @ AO_OFF   (attention out, channel-contiguous)
#define XT_OFF 0ull
#define WQ_OFF 4194304ull
#define WO_OFF 4980736ull
#define Q_OFF  5242880ull
#define K_OFF  9437184ull
#define V_OFF  13631488ull
#define AO_OFF 17825792ull

typedef __attribute__((ext_vector_type(8))) short bf16x8;
typedef __attribute__((ext_vector_type(4))) float f32x4;

__device__ __forceinline__ ushort f2bf(float f) {
    __hip_bfloat16 h = __float2bfloat16(f);
    return *reinterpret_cast<ushort*>(&h);
}

// ---------------------------------------------------------------------------
// Prep 1: transpose x [b][c][s] fp32 -> xT [b][s][c] bf16 via LDS tile.
// ---------------------------------------------------------------------------
__global__ __launch_bounds__(256) void transpose_x(const float* __restrict__ x,
                                                   ushort* __restrict__ xT) {
    const int s0 = blockIdx.x * 64, c0 = blockIdx.y * 64, b = blockIdx.z;
    const int tid = threadIdx.x;
    __shared__ float T[64][68];

    const float* xb = x + (size_t)b * C * S;
    #pragma unroll
    for (int i = 0; i < 4; ++i) {
        int idx = tid + i * 256;
        int row = idx >> 4, sv = idx & 15;
        *(float4*)&T[row][sv * 4] =
            *(const float4*)&xb[(size_t)(c0 + row) * S + s0 + sv * 4];
    }
    __syncthreads();
    #pragma unroll
    for (int i = 0; i < 2; ++i) {
        int idx = tid + i * 256;
        int orow = idx >> 3, och = idx & 7;
        ushort tmp[8];
        #pragma unroll
        for (int j = 0; j < 8; ++j) tmp[j] = f2bf(T[och * 8 + j][orow]);
        ushort* dst = &xT[((size_t)b * S + s0 + orow) * C + c0 + och * 8];
        *(ushort4*)&dst[0] = *(ushort4*)&tmp[0];
        *(ushort4*)&dst[4] = *(ushort4*)&tmp[4];
    }
}

// ---------------------------------------------------------------------------
// Prep 2: fp32 -> bf16 elementwise (weights).
// ---------------------------------------------------------------------------
__global__ __launch_bounds__(256) void conv_bf16(const float* __restrict__ src,
                                                 ushort* __restrict__ dst, int n4) {
    int idx = blockIdx.x * 256 + threadIdx.x;
    if (idx < n4) {
        float4 v = *(const float4*)&src[(size_t)idx * 4];
        ushort4 o = {f2bf(v.x), f2bf(v.y), f2bf(v.z), f2bf(v.w)};
        *(ushort4*)&dst[(size_t)idx * 4] = o;
    }
}

// ---------------------------------------------------------------------------
// Kernel: QKV projection, bf16 MFMA (unchanged from R4).
// ---------------------------------------------------------------------------
__global__ __launch_bounds__(256) void qkv_mfma(const ushort* __restrict__ xT,
                                                const ushort* __restrict__ wq,
                                                ushort* __restrict__ ws) {
    const int m0 = blockIdx.x * 128;
    const int o0 = blockIdx.y * 128;
    const int b  = blockIdx.z;
    const int tid = threadIdx.x;
    const int w = tid >> 6, l = tid & 63;
    const int l15 = l & 15, l4 = l >> 4;
    const int wr = w >> 1, wc = w & 1;

    __shared__ __align__(16) ushort At[128][72];
    __shared__ __align__(16) ushort Bt[128][72];

    const ushort* Ag = xT + ((size_t)b * S + m0) * C;
    const ushort* Bg = wq + (size_t)o0 * C;

    f32x4 acc[4][4];
    #pragma unroll
    for (int i = 0; i < 4; ++i)
        #pragma unroll
        for (int j = 0; j < 4; ++j) acc[i][j] = (f32x4){0.f, 0.f, 0.f, 0.f};

    for (int k0 = 0; k0 < C; k0 += 64) {
        if (k0) __syncthreads();
        #pragma unroll
        for (int i = 0; i < 4; ++i) {
            int idx = tid + i * 256;
            int row = idx >> 3, ch = idx & 7;
            *(bf16x8*)&At[row][ch * 8] =
                *(const bf16x8*)&Ag[(size_t)row * C + k0 + ch * 8];
            *(bf16x8*)&Bt[row][ch * 8] =
                *(const bf16x8*)&Bg[(size_t)row * C + k0 + ch * 8];
        }
        __syncthreads();
        #pragma unroll
        for (int c = 0; c < 2; ++c) {
            bf16x8 af[4], bfr[4];
            #pragma unroll
            for (int i = 0; i < 4; ++i) {
                af[i]  = *(const bf16x8*)&At[wr * 64 + i * 16 + l15][c * 32 + l4 * 8];
                bfr[i] = *(const bf16x8*)&Bt[wc * 64 + i * 16 + l15][c * 32 + l4 * 8];
            }
            #pragma unroll
            for (int i = 0; i < 4; ++i)
                #pragma unroll
                for (int j = 0; j < 4; ++j)
                    acc[i][j] = __builtin_amdgcn_mfma_f32_16x16x32_bf16(
                        af[i], bfr[j], acc[i][j], 0, 0, 0);
        }
    }

    const int t = o0 >> 9;
    #pragma unroll
    for (int j = 0; j < 4; ++j) {
        const int ob = o0 + wc * 64 + j * 16;
        const int h  = (ob & 511) >> 6;
        const int d0 = (ob & 63) + l15;
        if (t < 2) {
            ushort* dst = ws + (t == 0 ? Q_OFF : K_OFF) + (size_t)(b * H + h) * S * D;
            #pragma unroll
            for (int i = 0; i < 4; ++i) {
                #pragma unroll
                for (int r = 0; r < 4; ++r) {
                    int m = m0 + wr * 64 + i * 16 + l4 * 4 + r;
                    dst[(size_t)m * D + d0] = f2bf(acc[i][j][r]);
                }
            }
        } else {
            ushort* dst = ws + V_OFF + (size_t)(b * H + h) * D * S + (size_t)d0 * S;
            #pragma unroll
            for (int i = 0; i < 4; ++i) {
                int m = m0 + wr * 64 + i * 16 + l4 * 4;
                ushort4 pk = {f2bf(acc[i][j][0]), f2bf(acc[i][j][1]),
                              f2bf(acc[i][j][2]), f2bf(acc[i][j][3])};
                *(ushort4*)&dst[m] = pk;
            }
        }
    }
}

// ---------------------------------------------------------------------------
// Kernel: bf16 MFMA flash attention, v3.
// QBLK=64 (4 waves x 16 q-rows), KVBLK=128 (32 iters).
// Swapped QK^T: S^T = mfma(K,Q) -> lane owns q-row (q=l&15), kv on
// (nt,l4,reg). Row max/sum = in-lane + 2 shfl_xor. P never touches LDS:
// PV computed as O^T = mfma(V^T, P); the B-frag slot (c,l4,j) maps to
// in-lane value (nt=2c+(j>>2), reg=j&3) because V^T is staged with the
// matching kv-column permutation pi(t) (dot over kv is permutation-
// invariant). Defer-max (8 nats), reg-prefetch staging, setprio.
// ---------------------------------------------------------------------------
__global__ __launch_bounds__(256) void attn_kernel(const ushort* __restrict__ wsb,
                                                   ushort* __restrict__ aob) {
    const int q0 = blockIdx.x * 64;
    const int h  = blockIdx.y;
    const int b  = blockIdx.z;
    const int tid = threadIdx.x;
    const int w   = tid >> 6;
    const int l   = tid & 63;
    const int l15 = l & 15, l4 = l >> 4;

    const size_t bh = (size_t)(b * H + h);
    const ushort* qg = wsb + Q_OFF + bh * S * D;
    const ushort* kg = wsb + K_OFF + bh * S * D;
    const ushort* vg = wsb + V_OFF + bh * D * S;   // [D][S]

    __shared__ __align__(16) ushort Kt[128][72];   // [kv][d]
    __shared__ __align__(16) ushort Vt[64][136];   // [d][t], t = pi-permuted kv

    // Q B-frags (rows = q on l15)
    bf16x8 b_q[2];
    {
        int row = q0 + w * 16 + l15;
        b_q[0] = *(const bf16x8*)&qg[(size_t)row * D + l4 * 8];
        b_q[1] = *(const bf16x8*)&qg[(size_t)row * D + 32 + l4 * 8];
    }

    // O^T accumulator: o_acc[dt][reg] = O^T[d = dt*16 + l4*4 + reg][q = l15]
    f32x4 o_acc[4];
    #pragma unroll
    for (int dt = 0; dt < 4; ++dt) o_acc[dt] = (f32x4){0.f, 0.f, 0.f, 0.f};
    float m_run = -1e30f, l_run = 0.f;

    const f32x4 zero4 = (f32x4){0.f, 0.f, 0.f, 0.f};

    // staging maps
    const int krow = tid >> 3, kch = tid & 7;        // K: rows krow+32p, col kch*8
    const int vrow = tid >> 4, vtch = tid & 15;      // V: rows vrow+16p, t0 = vtch*8
    const int vc = vtch >> 2, vl4 = vtch & 3;

    bf16x8 kst[4];
    ushort4 vst[4][2];

    // prologue: stage tile 0
    #pragma unroll
    for (int p = 0; p < 4; ++p) {
        kst[p] = *(const bf16x8*)&kg[(size_t)(krow + p * 32) * D + kch * 8];
        #pragma unroll
        for (int jj = 0; jj < 2; ++jj)
            vst[p][jj] = *(const ushort4*)&vg[(size_t)(vrow + p * 16) * S +
                                              (2 * vc + jj) * 16 + vl4 * 4];
    }

    const int NT = S / 128;
    for (int kt = 0; kt < NT; ++kt) {
        // write staged tile (compiler inserts vmcnt waits)
        #pragma unroll
        for (int p = 0; p < 4; ++p) {
            *(bf16x8*)&Kt[krow + p * 32][kch * 8] = kst[p];
            #pragma unroll
            for (int jj = 0; jj < 2; ++jj)
                *(ushort4*)&Vt[vrow + p * 16][vtch * 8 + jj * 4] = vst[p][jj];
        }
        __syncthreads();

        // prefetch next tile into regs; hides under compute
        if (kt + 1 < NT) {
            #pragma unroll
            for (int p = 0; p < 4; ++p) {
                kst[p] = *(const bf16x8*)&kg[(size_t)((kt + 1) * 128 + krow + p * 32) * D + kch * 8];
                #pragma unroll
                for (int jj = 0; jj < 2; ++jj)
                    vst[p][jj] = *(const ushort4*)&vg[(size_t)(vrow + p * 16) * S +
                                                      (kt + 1) * 128 + (2 * vc + jj) * 16 + vl4 * 4];
            }
        }

        // ---- S^T = K Q^T : s[nt][reg] = S[q=l15][kv = nt*16 + l4*4 + reg] ----
        f32x4 s[8];
        __builtin_amdgcn_s_setprio(1);
        #pragma unroll
        for (int nt = 0; nt < 8; ++nt) {
            bf16x8 ak0 = *(const bf16x8*)&Kt[nt * 16 + l15][l4 * 8];
            bf16x8 ak1 = *(const bf16x8*)&Kt[nt * 16 + l15][32 + l4 * 8];
            f32x4 t = __builtin_amdgcn_mfma_f32_16x16x32_bf16(ak0, b_q[0], zero4, 0, 0, 0);
            s[nt] = __builtin_amdgcn_mfma_f32_16x16x32_bf16(ak1, b_q[1], t, 0, 0, 0);
        }
        __builtin_amdgcn_s_setprio(0);

        // ---- row max: in-lane (32 vals) + cross-l4 combine ----
        float mt = s[0][0];
        #pragma unroll
        for (int nt = 0; nt < 8; ++nt)
            #pragma unroll
            for (int reg = 0; reg < 4; ++reg) mt = fmaxf(mt, s[nt][reg]);
        mt = fmaxf(mt, __shfl_xor(mt, 16, 64));
        mt = fmaxf(mt, __shfl_xor(mt, 32, 64));

        // ---- defer-max rescale ----
        bool ok = (mt <= m_run + THR_RAW);
        if (!__all(ok)) {
            float mn = fmaxf(m_run, mt);
            float alpha = __builtin_amdgcn_exp2f((m_run - mn) * E2);
            m_run = mn;
            l_run *= alpha;
            #pragma unroll
            for (int dt = 0; dt < 4; ++dt)
                #pragma unroll
                for (int reg = 0; reg < 4; ++reg) o_acc[dt][reg] *= alpha;
        }

        // ---- P = exp(S - m) in-place; in-lane partial sum ----
        float msc = m_run * E2;
        float lt = 0.f;
        #pragma unroll
        for (int nt = 0; nt < 8; ++nt)
            #pragma unroll
            for (int reg = 0; reg < 4; ++reg) {
                float p = __builtin_amdgcn_exp2f(fmaf(s[nt][reg], E2, -msc));
                s[nt][reg] = p;
                lt += p;
            }
        lt += __shfl_xor(lt, 16, 64);
        lt += __shfl_xor(lt, 32, 64);
        l_run += lt;

        // ---- pack P to bf16 words: pw[nt][rp] = (p[2rp+1]<<16)|p[2rp] ----
        unsigned int pw[8][2];
        #pragma unroll
        for (int nt = 0; nt < 8; ++nt)
            #pragma unroll
            for (int rp = 0; rp < 2; ++rp)
                pw[nt][rp] = (unsigned int)f2bf(s[nt][2 * rp]) |
                             ((unsigned int)f2bf(s[nt][2 * rp + 1]) << 16);

        // ---- O^T += V^T P : pb slot (c,l4,j) = value (nt=2c+(j>>2), reg=j&3) ----
        __builtin_amdgcn_s_setprio(1);
        #pragma unroll
        for (int c = 0; c < 4; ++c) {
            union { unsigned int u[4]; bf16x8 v; } pbu;
            pbu.u[0] = pw[2 * c][0];
            pbu.u[1] = pw[2 * c][1];
            pbu.u[2] = pw[2 * c + 1][0];
            pbu.u[3] = pw[2 * c + 1][1];
            #pragma unroll
            for (int dt = 0; dt < 4; ++dt) {
                bf16x8 av = *(const bf16x8*)&Vt[dt * 16 + l15][c * 32 + l4 * 8];
                o_acc[dt] = __builtin_amdgcn_mfma_f32_16x16x32_bf16(
                    av, pbu.v, o_acc[dt], 0, 0, 0);
            }
        }
        __builtin_amdgcn_s_setprio(0);
        __syncthreads();
    }

    // ---- epilogue: normalize, store bf16 ao[b][s][c] (4x ushort4) ----
    float inv = 1.0f / l_run;
    int row = q0 + w * 16 + l15;
    #pragma unroll
    for (int dt = 0; dt < 4; ++dt) {
        ushort4 pk = {f2bf(o_acc[dt][0] * inv), f2bf(o_acc[dt][1] * inv),
                      f2bf(o_acc[dt][2] * inv), f2bf(o_acc[dt][3] * inv)};
        *(ushort4*)&aob[((size_t)b * S + row) * C + h * 64 + dt * 16 + l4 * 4] = pk;
    }
}

// ---------------------------------------------------------------------------
// Kernel: output projection, bf16 MFMA, + bias, fp32 out [b][c][s]
// (unchanged from R4).
// ---------------------------------------------------------------------------
__global__ __launch_bounds__(256) void oproj_mfma(const ushort* __restrict__ wo,
                                                  const ushort* __restrict__ aob,
                                                  const float* __restrict__ b_out,
                                                  float* __restrict__ out) {
    const int cc0 = blockIdx.x * 128;
    const int n0  = blockIdx.y * 128;
    const int b   = blockIdx.z;
    const int tid = threadIdx.x;
    const int w = tid >> 6, l = tid & 63;
    const int l15 = l & 15, l4 = l >> 4;
    const int wr = w >> 1, wc = w & 1;

    __shared__ __align__(16) ushort At[128][72];
    __shared__ __align__(16) ushort Bt[128][72];

    const ushort* Ag = wo + (size_t)cc0 * C;
    const ushort* Bg = aob + ((size_t)b * S + n0) * C;

    f32x4 acc[4][4];
    #pragma unroll
    for (int i = 0; i < 4; ++i)
        #pragma unroll
        for (int j = 0; j < 4; ++j) acc[i][j] = (f32x4){0.f, 0.f, 0.f, 0.f};

    for (int k0 = 0; k0 < C; k0 += 64) {
        if (k0) __syncthreads();
        #pragma unroll
        for (int i = 0; i < 4; ++i) {
            int idx = tid + i * 256;
            int row = idx >> 3, ch = idx & 7;
            *(bf16x8*)&At[row][ch * 8] =
                *(const bf16x8*)&Ag[(size_t)row * C + k0 + ch * 8];
            *(bf16x8*)&Bt[row][ch * 8] =
                *(const bf16x8*)&Bg[(size_t)row * C + k0 + ch * 8];
        }
        __syncthreads();
        #pragma unroll
        for (int c = 0; c < 2; ++c) {
            bf16x8 af[4], bfr[4];
            #pragma unroll
            for (int i = 0; i < 4; ++i) {
                af[i]  = *(const bf16x8*)&At[wr * 64 + i * 16 + l15][c * 32 + l4 * 8];
                bfr[i] = *(const bf16x8*)&Bt[wc * 64 + i * 16 + l15][c * 32 + l4 * 8];
            }
            #pragma unroll
            for (int i = 0; i < 4; ++i)
                #pragma unroll
                for (int j = 0; j < 4; ++j)
                    acc[i][j] = __builtin_amdgcn_mfma_f32_16x16x32_bf16(
                        af[i], bfr[j], acc[i][j], 0, 0, 0);
        }
    }

    #pragma unroll
    for (int i = 0; i < 4; ++i) {
        #pragma unroll
        for (int r = 0; r < 4; ++r) {
            int cc = cc0 + wr * 64 + i * 16 + l4 * 4 + r;
            float bias = b_out[cc];
            #pragma unroll
            for (int j = 0; j < 4; ++j) {
                int mm = n0 + wc * 64 + j * 16 + l15;
                out[((size_t)b * C + cc) * S + mm] = acc[i][j][r] + bias;
            }
        }
    }
}

// ---------------------------------------------------------------------------
extern "C" void kernel_launch(void* const* d_in, const int* in_sizes, int n_in,
                              void* d_out, int out_size, void* d_ws, size_t ws_size,
                              hipStream_t stream) {
    (void)in_sizes; (void)n_in; (void)out_size; (void)ws_size;
    const float* x     = (const float*)d_in[0];
    const float* w_qkv = (const float*)d_in[1];
    const float* w_out = (const float*)d_in[2];
    const float* b_out = (const float*)d_in[3];
    float* out = (float*)d_out;
    ushort* wsb = (ushort*)d_ws;    // 44 MB used

    transpose_x<<<dim3(S / 64, C / 64, B), 256, 0, stream>>>(x, wsb + XT_OFF);
    conv_bf16<<<dim3((O3 * C / 4 + 255) / 256), 256, 0, stream>>>(w_qkv, wsb + WQ_OFF, O3 * C / 4);
    conv_bf16<<<dim3((C * C / 4 + 255) / 256), 256, 0, stream>>>(w_out, wsb + WO_OFF, C * C / 4);
    qkv_mfma<<<dim3(S / 128, O3 / 128, B), 256, 0, stream>>>(wsb + XT_OFF, wsb + WQ_OFF, wsb);
    attn_kernel<<<dim3(S / 64, H, B), 256, 0, stream>>>(wsb, wsb + AO_OFF);
    oproj_mfma<<<dim3(C / 128, S / 128, B), 256, 0, stream>>>(wsb + WO_OFF, wsb + AO_OFF, b_out, out);
}

// Round 7
// 156.560 us; speedup vs baseline: 13.6579x; 1.2470x over previous
//
#include <hip/hip_runtime.h>
#include <hip/hip_bf16.h>

// Problem constants
#define B 2
#define C 512
#define H 8
#define D 64
#define S 4096           // 64*64 tokens
#define O3 1536          // 3*C
#define E2 0.18033688011112042f   // SCALE * log2(e),  SCALE = D^-0.5 = 0.125
#define THR_RAW 64.0f    // defer-max threshold: 8 nats / SCALE

// Workspace layout (ushort offsets; total 22,020,096 ushorts = 44 MB):
//   xT : bf16 [B][S][C]    @ XT_OFF   (x transposed, k-contiguous)
//   wq : bf16 [O3][C]      @ WQ_OFF
//   wo : bf16 [C][C]       @ WO_OFF
//   q  : bf16 [B][H][S][D] @ Q_OFF
//   k  : bf16 [B][H][S][D] @ K_OFF
//   v  : bf16 [B][H][D][S] @ V_OFF    (transposed: d-major)
//   ao : bf16 [B][S][C]    @ AO_OFF   (attention out, channel-contiguous)
#define XT_OFF 0ull
#define WQ_OFF 4194304ull
#define WO_OFF 4980736ull
#define Q_OFF  5242880ull
#define K_OFF  9437184ull
#define V_OFF  13631488ull
#define AO_OFF 17825792ull

typedef __attribute__((ext_vector_type(8))) short bf16x8;
typedef __attribute__((ext_vector_type(4))) float f32x4;

__device__ __forceinline__ ushort f2bf(float f) {
    __hip_bfloat16 h = __float2bfloat16(f);
    return *reinterpret_cast<ushort*>(&h);
}

// ---------------------------------------------------------------------------
// Prep 1: transpose x [b][c][s] fp32 -> xT [b][s][c] bf16 via LDS tile.
// ---------------------------------------------------------------------------
__global__ __launch_bounds__(256) void transpose_x(const float* __restrict__ x,
                                                   ushort* __restrict__ xT) {
    const int s0 = blockIdx.x * 64, c0 = blockIdx.y * 64, b = blockIdx.z;
    const int tid = threadIdx.x;
    __shared__ float T[64][68];

    const float* xb = x + (size_t)b * C * S;
    #pragma unroll
    for (int i = 0; i < 4; ++i) {
        int idx = tid + i * 256;
        int row = idx >> 4, sv = idx & 15;
        *(float4*)&T[row][sv * 4] =
            *(const float4*)&xb[(size_t)(c0 + row) * S + s0 + sv * 4];
    }
    __syncthreads();
    #pragma unroll
    for (int i = 0; i < 2; ++i) {
        int idx = tid + i * 256;
        int orow = idx >> 3, och = idx & 7;
        ushort tmp[8];
        #pragma unroll
        for (int j = 0; j < 8; ++j) tmp[j] = f2bf(T[och * 8 + j][orow]);
        ushort* dst = &xT[((size_t)b * S + s0 + orow) * C + c0 + och * 8];
        *(ushort4*)&dst[0] = *(ushort4*)&tmp[0];
        *(ushort4*)&dst[4] = *(ushort4*)&tmp[4];
    }
}

// ---------------------------------------------------------------------------
// Prep 2: fp32 -> bf16 elementwise (weights).
// ---------------------------------------------------------------------------
__global__ __launch_bounds__(256) void conv_bf16(const float* __restrict__ src,
                                                 ushort* __restrict__ dst, int n4) {
    int idx = blockIdx.x * 256 + threadIdx.x;
    if (idx < n4) {
        float4 v = *(const float4*)&src[(size_t)idx * 4];
        ushort4 o = {f2bf(v.x), f2bf(v.y), f2bf(v.z), f2bf(v.w)};
        *(ushort4*)&dst[(size_t)idx * 4] = o;
    }
}

// ---------------------------------------------------------------------------
// Kernel: QKV projection, bf16 MFMA (unchanged from R4).
// ---------------------------------------------------------------------------
__global__ __launch_bounds__(256) void qkv_mfma(const ushort* __restrict__ xT,
                                                const ushort* __restrict__ wq,
                                                ushort* __restrict__ ws) {
    const int m0 = blockIdx.x * 128;
    const int o0 = blockIdx.y * 128;
    const int b  = blockIdx.z;
    const int tid = threadIdx.x;
    const int w = tid >> 6, l = tid & 63;
    const int l15 = l & 15, l4 = l >> 4;
    const int wr = w >> 1, wc = w & 1;

    __shared__ __align__(16) ushort At[128][72];
    __shared__ __align__(16) ushort Bt[128][72];

    const ushort* Ag = xT + ((size_t)b * S + m0) * C;
    const ushort* Bg = wq + (size_t)o0 * C;

    f32x4 acc[4][4];
    #pragma unroll
    for (int i = 0; i < 4; ++i)
        #pragma unroll
        for (int j = 0; j < 4; ++j) acc[i][j] = (f32x4){0.f, 0.f, 0.f, 0.f};

    for (int k0 = 0; k0 < C; k0 += 64) {
        if (k0) __syncthreads();
        #pragma unroll
        for (int i = 0; i < 4; ++i) {
            int idx = tid + i * 256;
            int row = idx >> 3, ch = idx & 7;
            *(bf16x8*)&At[row][ch * 8] =
                *(const bf16x8*)&Ag[(size_t)row * C + k0 + ch * 8];
            *(bf16x8*)&Bt[row][ch * 8] =
                *(const bf16x8*)&Bg[(size_t)row * C + k0 + ch * 8];
        }
        __syncthreads();
        #pragma unroll
        for (int c = 0; c < 2; ++c) {
            bf16x8 af[4], bfr[4];
            #pragma unroll
            for (int i = 0; i < 4; ++i) {
                af[i]  = *(const bf16x8*)&At[wr * 64 + i * 16 + l15][c * 32 + l4 * 8];
                bfr[i] = *(const bf16x8*)&Bt[wc * 64 + i * 16 + l15][c * 32 + l4 * 8];
            }
            #pragma unroll
            for (int i = 0; i < 4; ++i)
                #pragma unroll
                for (int j = 0; j < 4; ++j)
                    acc[i][j] = __builtin_amdgcn_mfma_f32_16x16x32_bf16(
                        af[i], bfr[j], acc[i][j], 0, 0, 0);
        }
    }

    const int t = o0 >> 9;
    #pragma unroll
    for (int j = 0; j < 4; ++j) {
        const int ob = o0 + wc * 64 + j * 16;
        const int h  = (ob & 511) >> 6;
        const int d0 = (ob & 63) + l15;
        if (t < 2) {
            ushort* dst = ws + (t == 0 ? Q_OFF : K_OFF) + (size_t)(b * H + h) * S * D;
            #pragma unroll
            for (int i = 0; i < 4; ++i) {
                #pragma unroll
                for (int r = 0; r < 4; ++r) {
                    int m = m0 + wr * 64 + i * 16 + l4 * 4 + r;
                    dst[(size_t)m * D + d0] = f2bf(acc[i][j][r]);
                }
            }
        } else {
            ushort* dst = ws + V_OFF + (size_t)(b * H + h) * D * S + (size_t)d0 * S;
            #pragma unroll
            for (int i = 0; i < 4; ++i) {
                int m = m0 + wr * 64 + i * 16 + l4 * 4;
                ushort4 pk = {f2bf(acc[i][j][0]), f2bf(acc[i][j][1]),
                              f2bf(acc[i][j][2]), f2bf(acc[i][j][3])};
                *(ushort4*)&dst[m] = pk;
            }
        }
    }
}

// ---------------------------------------------------------------------------
// Kernel: bf16 MFMA flash attention, v4.
// QBLK=128, 8 waves (512 thr) x 16 q-rows; KVBLK=128 (32 iters).
// Same per-wave math as v3 (swapped QK^T, pi-permuted V^T, in-reg P,
// defer-max, reg-prefetch staging, setprio) but the K/V LDS tile is shared
// by 8 waves: staging instr/score and barriers/score halve; 2 blocks/CU at
// ~80 VGPR -> 16 waves/CU (4/SIMD) for latency hiding. l-sum shuffles
// hoisted to the epilogue (lane-partial l_run).
// ---------------------------------------------------------------------------
__global__ __launch_bounds__(512) void attn_kernel(const ushort* __restrict__ wsb,
                                                   ushort* __restrict__ aob) {
    const int q0 = blockIdx.x * 128;
    const int h  = blockIdx.y;
    const int b  = blockIdx.z;
    const int tid = threadIdx.x;
    const int w   = tid >> 6;
    const int l   = tid & 63;
    const int l15 = l & 15, l4 = l >> 4;

    const size_t bh = (size_t)(b * H + h);
    const ushort* qg = wsb + Q_OFF + bh * S * D;
    const ushort* kg = wsb + K_OFF + bh * S * D;
    const ushort* vg = wsb + V_OFF + bh * D * S;   // [D][S]

    __shared__ __align__(16) ushort Kt[128][72];   // [kv][d]
    __shared__ __align__(16) ushort Vt[64][136];   // [d][t], t = pi-permuted kv

    // Q B-frags (rows = q on l15)
    bf16x8 b_q[2];
    {
        int row = q0 + w * 16 + l15;
        b_q[0] = *(const bf16x8*)&qg[(size_t)row * D + l4 * 8];
        b_q[1] = *(const bf16x8*)&qg[(size_t)row * D + 32 + l4 * 8];
    }

    // O^T accumulator: o_acc[dt][reg] = O^T[d = dt*16 + l4*4 + reg][q = l15]
    f32x4 o_acc[4];
    #pragma unroll
    for (int dt = 0; dt < 4; ++dt) o_acc[dt] = (f32x4){0.f, 0.f, 0.f, 0.f};
    float m_run = -1e30f, l_run = 0.f;   // l_run is a LANE-PARTIAL sum

    const f32x4 zero4 = (f32x4){0.f, 0.f, 0.f, 0.f};

    // staging maps (512 threads)
    const int krow = tid >> 3, kch = tid & 7;        // K: rows krow, krow+64
    const int vrow = tid >> 4, vtch = tid & 15;      // V: rows vrow, vrow+32
    const int vc = vtch >> 2, vl4 = vtch & 3;

    bf16x8 kst[2];
    ushort4 vst[2][2];

    // prologue: stage tile 0
    #pragma unroll
    for (int p = 0; p < 2; ++p) {
        kst[p] = *(const bf16x8*)&kg[(size_t)(krow + p * 64) * D + kch * 8];
        #pragma unroll
        for (int jj = 0; jj < 2; ++jj)
            vst[p][jj] = *(const ushort4*)&vg[(size_t)(vrow + p * 32) * S +
                                              (2 * vc + jj) * 16 + vl4 * 4];
    }

    const int NT = S / 128;
    for (int kt = 0; kt < NT; ++kt) {
        // write staged tile (compiler inserts vmcnt waits)
        #pragma unroll
        for (int p = 0; p < 2; ++p) {
            *(bf16x8*)&Kt[krow + p * 64][kch * 8] = kst[p];
            #pragma unroll
            for (int jj = 0; jj < 2; ++jj)
                *(ushort4*)&Vt[vrow + p * 32][vtch * 8 + jj * 4] = vst[p][jj];
        }
        __syncthreads();

        // prefetch next tile into regs; hides under compute
        if (kt + 1 < NT) {
            #pragma unroll
            for (int p = 0; p < 2; ++p) {
                kst[p] = *(const bf16x8*)&kg[(size_t)((kt + 1) * 128 + krow + p * 64) * D + kch * 8];
                #pragma unroll
                for (int jj = 0; jj < 2; ++jj)
                    vst[p][jj] = *(const ushort4*)&vg[(size_t)(vrow + p * 32) * S +
                                                      (kt + 1) * 128 + (2 * vc + jj) * 16 + vl4 * 4];
            }
        }

        // ---- S^T = K Q^T : s[nt][reg] = S[q=l15][kv = nt*16 + l4*4 + reg] ----
        f32x4 s[8];
        __builtin_amdgcn_s_setprio(1);
        #pragma unroll
        for (int nt = 0; nt < 8; ++nt) {
            bf16x8 ak0 = *(const bf16x8*)&Kt[nt * 16 + l15][l4 * 8];
            bf16x8 ak1 = *(const bf16x8*)&Kt[nt * 16 + l15][32 + l4 * 8];
            f32x4 t = __builtin_amdgcn_mfma_f32_16x16x32_bf16(ak0, b_q[0], zero4, 0, 0, 0);
            s[nt] = __builtin_amdgcn_mfma_f32_16x16x32_bf16(ak1, b_q[1], t, 0, 0, 0);
        }
        __builtin_amdgcn_s_setprio(0);

        // ---- row max: in-lane (32 vals) + cross-l4 combine ----
        float mt = s[0][0];
        #pragma unroll
        for (int nt = 0; nt < 8; ++nt)
            #pragma unroll
            for (int reg = 0; reg < 4; ++reg) mt = fmaxf(mt, s[nt][reg]);
        mt = fmaxf(mt, __shfl_xor(mt, 16, 64));
        mt = fmaxf(mt, __shfl_xor(mt, 32, 64));

        // ---- defer-max rescale ----
        bool ok = (mt <= m_run + THR_RAW);
        if (!__all(ok)) {
            float mn = fmaxf(m_run, mt);
            float alpha = __builtin_amdgcn_exp2f((m_run - mn) * E2);
            m_run = mn;
            l_run *= alpha;
            #pragma unroll
            for (int dt = 0; dt < 4; ++dt)
                #pragma unroll
                for (int reg = 0; reg < 4; ++reg) o_acc[dt][reg] *= alpha;
        }

        // ---- P = exp(S - m) in-place; lane-partial sum (no shuffles) ----
        float msc = m_run * E2;
        #pragma unroll
        for (int nt = 0; nt < 8; ++nt)
            #pragma unroll
            for (int reg = 0; reg < 4; ++reg) {
                float p = __builtin_amdgcn_exp2f(fmaf(s[nt][reg], E2, -msc));
                s[nt][reg] = p;
                l_run += p;
            }

        // ---- pack P to bf16 words: pw[nt][rp] = (p[2rp+1]<<16)|p[2rp] ----
        unsigned int pw[8][2];
        #pragma unroll
        for (int nt = 0; nt < 8; ++nt)
            #pragma unroll
            for (int rp = 0; rp < 2; ++rp)
                pw[nt][rp] = (unsigned int)f2bf(s[nt][2 * rp]) |
                             ((unsigned int)f2bf(s[nt][2 * rp + 1]) << 16);

        // ---- O^T += V^T P : pb slot (c,l4,j) = value (nt=2c+(j>>2), reg=j&3) ----
        __builtin_amdgcn_s_setprio(1);
        #pragma unroll
        for (int c = 0; c < 4; ++c) {
            union { unsigned int u[4]; bf16x8 v; } pbu;
            pbu.u[0] = pw[2 * c][0];
            pbu.u[1] = pw[2 * c][1];
            pbu.u[2] = pw[2 * c + 1][0];
            pbu.u[3] = pw[2 * c + 1][1];
            #pragma unroll
            for (int dt = 0; dt < 4; ++dt) {
                bf16x8 av = *(const bf16x8*)&Vt[dt * 16 + l15][c * 32 + l4 * 8];
                o_acc[dt] = __builtin_amdgcn_mfma_f32_16x16x32_bf16(
                    av, pbu.v, o_acc[dt], 0, 0, 0);
            }
        }
        __builtin_amdgcn_s_setprio(0);
        __syncthreads();
    }

    // ---- epilogue: combine lane-partial l across l4 groups, normalize ----
    l_run += __shfl_xor(l_run, 16, 64);
    l_run += __shfl_xor(l_run, 32, 64);
    float inv = 1.0f / l_run;
    int row = q0 + w * 16 + l15;
    #pragma unroll
    for (int dt = 0; dt < 4; ++dt) {
        ushort4 pk = {f2bf(o_acc[dt][0] * inv), f2bf(o_acc[dt][1] * inv),
                      f2bf(o_acc[dt][2] * inv), f2bf(o_acc[dt][3] * inv)};
        *(ushort4*)&aob[((size_t)b * S + row) * C + h * 64 + dt * 16 + l4 * 4] = pk;
    }
}

// ---------------------------------------------------------------------------
// Kernel: output projection, bf16 MFMA, + bias, fp32 out [b][c][s]
// (unchanged from R4).
// ---------------------------------------------------------------------------
__global__ __launch_bounds__(256) void oproj_mfma(const ushort* __restrict__ wo,
                                                  const ushort* __restrict__ aob,
                                                  const float* __restrict__ b_out,
                                                  float* __restrict__ out) {
    const int cc0 = blockIdx.x * 128;
    const int n0  = blockIdx.y * 128;
    const int b   = blockIdx.z;
    const int tid = threadIdx.x;
    const int w = tid >> 6, l = tid & 63;
    const int l15 = l & 15, l4 = l >> 4;
    const int wr = w >> 1, wc = w & 1;

    __shared__ __align__(16) ushort At[128][72];
    __shared__ __align__(16) ushort Bt[128][72];

    const ushort* Ag = wo + (size_t)cc0 * C;
    const ushort* Bg = aob + ((size_t)b * S + n0) * C;

    f32x4 acc[4][4];
    #pragma unroll
    for (int i = 0; i < 4; ++i)
        #pragma unroll
        for (int j = 0; j < 4; ++j) acc[i][j] = (f32x4){0.f, 0.f, 0.f, 0.f};

    for (int k0 = 0; k0 < C; k0 += 64) {
        if (k0) __syncthreads();
        #pragma unroll
        for (int i = 0; i < 4; ++i) {
            int idx = tid + i * 256;
            int row = idx >> 3, ch = idx & 7;
            *(bf16x8*)&At[row][ch * 8] =
                *(const bf16x8*)&Ag[(size_t)row * C + k0 + ch * 8];
            *(bf16x8*)&Bt[row][ch * 8] =
                *(const bf16x8*)&Bg[(size_t)row * C + k0 + ch * 8];
        }
        __syncthreads();
        #pragma unroll
        for (int c = 0; c < 2; ++c) {
            bf16x8 af[4], bfr[4];
            #pragma unroll
            for (int i = 0; i < 4; ++i) {
                af[i]  = *(const bf16x8*)&At[wr * 64 + i * 16 + l15][c * 32 + l4 * 8];
                bfr[i] = *(const bf16x8*)&Bt[wc * 64 + i * 16 + l15][c * 32 + l4 * 8];
            }
            #pragma unroll
            for (int i = 0; i < 4; ++i)
                #pragma unroll
                for (int j = 0; j < 4; ++j)
                    acc[i][j] = __builtin_amdgcn_mfma_f32_16x16x32_bf16(
                        af[i], bfr[j], acc[i][j], 0, 0, 0);
        }
    }

    #pragma unroll
    for (int i = 0; i < 4; ++i) {
        #pragma unroll
        for (int r = 0; r < 4; ++r) {
            int cc = cc0 + wr * 64 + i * 16 + l4 * 4 + r;
            float bias = b_out[cc];
            #pragma unroll
            for (int j = 0; j < 4; ++j) {
                int mm = n0 + wc * 64 + j * 16 + l15;
                out[((size_t)b * C + cc) * S + mm] = acc[i][j][r] + bias;
            }
        }
    }
}

// ---------------------------------------------------------------------------
extern "C" void kernel_launch(void* const* d_in, const int* in_sizes, int n_in,
                              void* d_out, int out_size, void* d_ws, size_t ws_size,
                              hipStream_t stream) {
    (void)in_sizes; (void)n_in; (void)out_size; (void)ws_size;
    const float* x     = (const float*)d_in[0];
    const float* w_qkv = (const float*)d_in[1];
    const float* w_out = (const float*)d_in[2];
    const float* b_out = (const float*)d_in[3];
    float* out = (float*)d_out;
    ushort* wsb = (ushort*)d_ws;    // 44 MB used

    transpose_x<<<dim3(S / 64, C / 64, B), 256, 0, stream>>>(x, wsb + XT_OFF);
    conv_bf16<<<dim3((O3 * C / 4 + 255) / 256), 256, 0, stream>>>(w_qkv, wsb + WQ_OFF, O3 * C / 4);
    conv_bf16<<<dim3((C * C / 4 + 255) / 256), 256, 0, stream>>>(w_out, wsb + WO_OFF, C * C / 4);
    qkv_mfma<<<dim3(S / 128, O3 / 128, B), 256, 0, stream>>>(wsb + XT_OFF, wsb + WQ_OFF, wsb);
    attn_kernel<<<dim3(S / 128, H, B), 512, 0, stream>>>(wsb, wsb + AO_OFF);
    oproj_mfma<<<dim3(C / 128, S / 128, B), 256, 0, stream>>>(wsb + WO_OFF, wsb + AO_OFF, b_out, out);
}